// Round 5
// baseline (2559.476 us; speedup 1.0000x reference)
//
#include <hip/hip_runtime.h>
#include <math.h>

#define UNITS   128
#define NRBF    10
#define SBF     9
#define NLAYERS 3
#define NELEM   95
#define NTOTAL  60000
#define NLOCAL  50000
#define NGHOST  10000
#define NEDGE   250000
#define NTRIPLE 1000000
#define CUTOFF  5.0f
#define TBCUT   4.0f
#define PI_F    3.14159265358979323846f

typedef __attribute__((ext_vector_type(8))) short short8;
typedef __attribute__((ext_vector_type(4))) float f32x4;

// fast sigmoid/silu: v_exp_f32-based (__expf), ~1e-5 rel err — far below bf16 noise
__device__ __forceinline__ float sigm(float x){ return 1.0f/(1.0f+__expf(-x)); }
__device__ __forceinline__ float silu(float x){ return x/(1.0f+__expf(-x)); }
__device__ __forceinline__ float polycut(float r){
    float q = r*(1.0f/TBCUT);
    float q2 = q*q, q3 = q2*q;
    float p = 1.0f - 6.0f*q2*q3 + 15.0f*q2*q2 - 10.0f*q3;
    return (r <= TBCUT) ? p : 0.0f;
}
__device__ __forceinline__ ushort f2bf(float x){
    unsigned u = __float_as_uint(x);
    unsigned r = (u + 0x7fffu + ((u>>16)&1u)) >> 16;
    return (ushort)r;
}
__device__ __forceinline__ void fma4s(float4& acc, float s, const float4& v){
    acc.x = fmaf(s, v.x, acc.x);
    acc.y = fmaf(s, v.y, acc.y);
    acc.z = fmaf(s, v.z, acc.z);
    acc.w = fmaf(s, v.w, acc.w);
}

// ---------------- edge geometry + rbf ----------------
__global__ void k_edge_geom(const float* __restrict__ pos, const float* __restrict__ cell,
                            const float* __restrict__ pbc, const int* __restrict__ src,
                            const int* __restrict__ dst, const int* __restrict__ batch,
                            float* __restrict__ evec, float* __restrict__ elen,
                            float* __restrict__ rbf0){
    int e = blockIdx.x*blockDim.x + threadIdx.x;
    if (e >= NEDGE) return;
    int s = src[e], d = dst[e];
    int b = batch[s];
    const float* C = cell + b*9;
    float p0 = pbc[e*3+0], p1 = pbc[e*3+1], p2 = pbc[e*3+2];
    float vx = pos[s*3+0] - (pos[d*3+0] + p0*C[0] + p1*C[3] + p2*C[6]);
    float vy = pos[s*3+1] - (pos[d*3+1] + p0*C[1] + p1*C[4] + p2*C[7]);
    float vz = pos[s*3+2] - (pos[d*3+2] + p0*C[2] + p1*C[5] + p2*C[8]);
    float r = sqrtf(vx*vx + vy*vy + vz*vz);
    evec[e*3+0] = vx; evec[e*3+1] = vy; evec[e*3+2] = vz;
    elen[e] = r;
    #pragma unroll
    for (int i = 0; i < NRBF; i++){
        float mu = (CUTOFF/(NRBF-1))*i;
        float dm = r - mu;
        rbf0[e*NRBF + i] = __expf(-dm*dm*2.0f);
    }
}

// ---------------- atom embedding gather ----------------
__global__ void k_embed(const int* __restrict__ anum, const float* __restrict__ embw,
                        float* __restrict__ A){
    int t = blockIdx.x*blockDim.x + threadIdx.x;
    if (t >= NTOTAL*32) return;
    int a = t >> 5, q = t & 31;
    ((float4*)A)[t] = ((const float4*)embw)[anum[a]*32 + q];
}

// ---------------- edge encoding: E = rbf0 @ Wenc + benc ----------------
__global__ void k_edge_enc(const float* __restrict__ rbf0, const float* __restrict__ encw,
                           const float* __restrict__ encb, float* __restrict__ E){
    int t = blockIdx.x*blockDim.x + threadIdx.x;
    if (t >= NEDGE*32) return;
    int e = t >> 5, q = t & 31;
    float4 acc = ((const float4*)encb)[q];
    const float4* W4 = (const float4*)encw;
    #pragma unroll
    for (int r = 0; r < NRBF; r++){
        float rv = rbf0[e*NRBF + r];
        fma4s(acc, rv, W4[r*32 + q]);
    }
    ((float4*)E)[t] = acc;
}

// ---------------- pack gated-MLP weights into MFMA B-fragment layout ----------------
// layout: [L][mat(ge_m,ge_g,ga_m,ga_g)][kb:12][nt:8][lane:64][j:8] bf16
__global__ void k_pack_w(const float* __restrict__ gewm, const float* __restrict__ gewg,
                         const float* __restrict__ gawm, const float* __restrict__ gawg,
                         ushort* __restrict__ wp){
    int t = blockIdx.x*blockDim.x + threadIdx.x;
    if (t >= 3*4*12*8*64) return;
    int lane = t & 63;
    int nt   = (t>>6) & 7;
    int rest = t >> 9;
    int kb   = rest % 12;
    int r2   = rest / 12;
    int mat  = r2 & 3;
    int L    = r2 >> 2;
    const float* src;
    if      (mat == 0) src = gewm;
    else if (mat == 1) src = gewg;
    else if (mat == 2) src = gawm;
    else               src = gawg;
    src += (size_t)L*384*128;
    int n = nt*16 + (lane & 15);
    int kbase = kb*32 + (lane>>4)*8;
    ushort* dst = wp + (size_t)t*8;
    #pragma unroll
    for (int j = 0; j < 8; j++) dst[j] = f2bf(src[(size_t)(kbase+j)*128 + n]);
}

// ---------------- per-layer: atom sbf mlp ----------------
__global__ void k_tb_mlp(const float* __restrict__ A, const float* __restrict__ W,
                         const float* __restrict__ b, float* __restrict__ out){
    int a = blockIdx.x*blockDim.x + threadIdx.x;
    if (a >= NLOCAL) return;
    float acc[SBF];
    #pragma unroll
    for (int s = 0; s < SBF; s++) acc[s] = b[s];
    const float4* row4 = (const float4*)(A + (size_t)a*UNITS);
    for (int k4 = 0; k4 < 32; k4++){
        float4 v = row4[k4];
        const float* w = W + (k4*4)*SBF;
        #pragma unroll
        for (int s = 0; s < SBF; s++){
            acc[s] = fmaf(v.x, w[s],        acc[s]);
            acc[s] = fmaf(v.y, w[s+SBF],    acc[s]);
            acc[s] = fmaf(v.z, w[s+2*SBF],  acc[s]);
            acc[s] = fmaf(v.w, w[s+3*SBF],  acc[s]);
        }
    }
    #pragma unroll
    for (int s = 0; s < SBF; s++) out[a*SBF + s] = sigm(acc[s]);
}

// ---------------- per-layer: triples -> scatter into tb_out ----------------
__global__ void k_triple(const float* __restrict__ evec, const float* __restrict__ elen,
                         const int* __restrict__ esrc, const int* __restrict__ tbi,
                         const float* __restrict__ amlp, float* __restrict__ tb_out){
    int t = blockIdx.x*blockDim.x + threadIdx.x;
    if (t >= NTRIPLE) return;
    int ij = tbi[2*t], ik = tbi[2*t+1];
    float rij = elen[ij], rik = elen[ik];
    float cutij = polycut(rij), cutik = polycut(rik);
    float cc = cutij*cutik;
    if (cc == 0.0f) return;
    float ax = evec[ij*3+0], ay = evec[ij*3+1], az = evec[ij*3+2];
    float bx = evec[ik*3+0], by = evec[ik*3+1], bz = evec[ik*3+2];
    float dot = ax*bx + ay*by + az*bz;
    float c = dot/(rij*rik + 1e-12f);
    c = fminf(fmaxf(c, -1.0f + 1e-7f), 1.0f - 1e-7f);
    float a0 = 1.0f, a1 = c, a2 = 2.0f*c*c - 1.0f;
    float x = rik*(PI_F/TBCUT);
    float s1, c1;
    sincosf(x, &s1, &c1);
    float s2 = 2.0f*s1*c1;
    float s3 = s1*(3.0f - 4.0f*s1*s1);
    float inv = 1.0f/(rik + 1e-6f);
    float r0 = s1*inv, r1 = s2*inv, r2 = s3*inv;
    int ka = esrc[ik];
    const float* am = amlp + (size_t)ka*SBF;
    float* dst = tb_out + (size_t)ij*SBF;
    atomicAdd(dst+0, r0*a0*am[0]*cc);
    atomicAdd(dst+1, r0*a1*am[1]*cc);
    atomicAdd(dst+2, r0*a2*am[2]*cc);
    atomicAdd(dst+3, r1*a0*am[3]*cc);
    atomicAdd(dst+4, r1*a1*am[4]*cc);
    atomicAdd(dst+5, r1*a2*am[5]*cc);
    atomicAdd(dst+6, r2*a0*am[6]*cc);
    atomicAdd(dst+7, r2*a1*am[7]*cc);
    atomicAdd(dst+8, r2*a2*am[8]*cc);
}

// ---------------- fused per-layer gated blocks (ge + ga) via bf16 MFMA ----------------
// 32 edges/block, 4 waves. feat = [A[src] | A[dst] | E+tbgate] bf16 in LDS (stride 392).
// Phase 1: full-K ge GEMM + A-part (K 0..255) of ga GEMM in one loop.
// Epilogue 1: E_new = E_old + tbgate_f32 + silu(m)sigm(g)*el_e ; write global E + LDS bf16.
// Phase 2: remaining K 256..383 of ga GEMM on E_new.
// Epilogue 2: agg[src] += silu(m)sigm(g)*el_a (device atomics).
// launch_bounds(256,5): 5 blocks/CU (LDS 28KB*5=140KB<160KB), 20 waves/CU for latency hiding.
__global__ __launch_bounds__(256, 5)
void k_gated_fused(const float* __restrict__ A, float* __restrict__ E,
                   const int* __restrict__ esrc, const int* __restrict__ edst,
                   const float* __restrict__ tb_out, const float* __restrict__ tbg,
                   const float* __restrict__ tbb,
                   const ushort* __restrict__ WemP, const ushort* __restrict__ WegP,
                   const ushort* __restrict__ WamP, const ushort* __restrict__ WagP,
                   const float* __restrict__ bem, const float* __restrict__ beg,
                   const float* __restrict__ elew_, const float* __restrict__ eleb_,
                   const float* __restrict__ bam, const float* __restrict__ bag,
                   const float* __restrict__ elaw_, const float* __restrict__ elab_,
                   const float* __restrict__ rbf0, float* __restrict__ agg){
    __shared__ __align__(16) ushort feat_s[32*392];
    __shared__ float rbf_s[32][NRBF];
    __shared__ float tb_s[32][SBF];
    __shared__ int   src_s[32];
    __shared__ int   dst_s[32];

    const int tid = threadIdx.x;
    const int e0  = blockIdx.x*32;

    if (tid < 32){
        int e = min(e0 + tid, NEDGE-1);
        src_s[tid] = esrc[e];
        dst_s[tid] = edst[e];
        #pragma unroll
        for (int r = 0; r < NRBF; r++) rbf_s[tid][r] = rbf0[(size_t)e*NRBF + r];
        #pragma unroll
        for (int s = 0; s < SBF; s++) tb_s[tid][s] = tb_out[(size_t)e*SBF + s];
    }
    __syncthreads();

    const float4* A4   = (const float4*)A;
    const float4* E4   = (const float4*)E;
    const float4* tbg4 = (const float4*)tbg;
    const float4* tbb4 = (const float4*)tbb;

    // stage feat: 32 rows x 96 float4 -> bf16, 12 pieces/thread
    #pragma unroll
    for (int j = 0; j < 12; j++){
        int idx = j*256 + tid;
        int m   = idx/96;
        int k4  = idx - m*96;
        float4 v;
        if (k4 < 32){
            v = A4[(size_t)src_s[m]*32 + k4];
        } else if (k4 < 64){
            v = A4[(size_t)dst_s[m]*32 + (k4-32)];
        } else {
            int q = k4 - 64;
            int e = min(e0 + m, NEDGE-1);
            v = E4[(size_t)e*32 + q];
            float4 tacc = tbb4[q];
            #pragma unroll
            for (int s = 0; s < SBF; s++) fma4s(tacc, tb_s[m][s], tbg4[s*32 + q]);
            v.x += tacc.x; v.y += tacc.y; v.z += tacc.z; v.w += tacc.w;
        }
        ushort4 h;
        h.x = f2bf(v.x); h.y = f2bf(v.y); h.z = f2bf(v.z); h.w = f2bf(v.w);
        *(ushort4*)&feat_s[m*392 + k4*4] = h;
    }
    __syncthreads();

    const int lane = tid & 63;
    const int w    = tid >> 6;
    const int quad = lane >> 4;
    const int l15  = lane & 15;

    f32x4 zero4 = {0.f, 0.f, 0.f, 0.f};
    f32x4 acc_em[2][2], acc_eg[2][2], acc_am[2][2], acc_ag[2][2];
    #pragma unroll
    for (int mt = 0; mt < 2; mt++)
        #pragma unroll
        for (int ct = 0; ct < 2; ct++){
            acc_em[mt][ct] = zero4; acc_eg[mt][ct] = zero4;
            acc_am[mt][ct] = zero4; acc_ag[mt][ct] = zero4;
        }

    const ushort* a0p = feat_s + l15*392 + quad*8;
    const ushort* a1p = a0p + 16*392;

    // Phase 1: ge over K 0..383; ga over K 0..255 (A-part only)
    for (int ks = 0; ks < 12; ks++){
        short8 a0 = *(const short8*)(a0p + ks*32);
        short8 a1 = *(const short8*)(a1p + ks*32);
        #pragma unroll
        for (int ct = 0; ct < 2; ct++){
            int nt = w*2 + ct;
            size_t boff = ((size_t)(ks*8 + nt)*64 + lane)*8;
            short8 b_em = *(const short8*)(WemP + boff);
            short8 b_eg = *(const short8*)(WegP + boff);
            acc_em[0][ct] = __builtin_amdgcn_mfma_f32_16x16x32_bf16(a0, b_em, acc_em[0][ct], 0, 0, 0);
            acc_em[1][ct] = __builtin_amdgcn_mfma_f32_16x16x32_bf16(a1, b_em, acc_em[1][ct], 0, 0, 0);
            acc_eg[0][ct] = __builtin_amdgcn_mfma_f32_16x16x32_bf16(a0, b_eg, acc_eg[0][ct], 0, 0, 0);
            acc_eg[1][ct] = __builtin_amdgcn_mfma_f32_16x16x32_bf16(a1, b_eg, acc_eg[1][ct], 0, 0, 0);
            if (ks < 8){
                short8 b_am = *(const short8*)(WamP + boff);
                short8 b_ag = *(const short8*)(WagP + boff);
                acc_am[0][ct] = __builtin_amdgcn_mfma_f32_16x16x32_bf16(a0, b_am, acc_am[0][ct], 0, 0, 0);
                acc_am[1][ct] = __builtin_amdgcn_mfma_f32_16x16x32_bf16(a1, b_am, acc_am[1][ct], 0, 0, 0);
                acc_ag[0][ct] = __builtin_amdgcn_mfma_f32_16x16x32_bf16(a0, b_ag, acc_ag[0][ct], 0, 0, 0);
                acc_ag[1][ct] = __builtin_amdgcn_mfma_f32_16x16x32_bf16(a1, b_ag, acc_ag[1][ct], 0, 0, 0);
            }
        }
    }

    // Epilogue 1: edge update
    {
        float bmv[2], bgv[2], elbv[2], elwv[2][NRBF], tbbv[2], tbgv[2][SBF];
        #pragma unroll
        for (int ct = 0; ct < 2; ct++){
            int c = w*32 + ct*16 + l15;
            bmv[ct]  = bem[c];
            bgv[ct]  = beg[c];
            elbv[ct] = eleb_[c];
            #pragma unroll
            for (int r = 0; r < NRBF; r++) elwv[ct][r] = elew_[r*UNITS + c];
            tbbv[ct] = tbb[c];
            #pragma unroll
            for (int s = 0; s < SBF; s++) tbgv[ct][s] = tbg[s*UNITS + c];
        }
        // all phase-1 LDS reads are done (loop above); safe to overwrite E-region after barrier
        __syncthreads();
        #pragma unroll
        for (int mt = 0; mt < 2; mt++){
            #pragma unroll
            for (int r = 0; r < 4; r++){
                int ml = mt*16 + quad*4 + r;
                int e  = e0 + ml;
                if (e >= NEDGE) continue;
                #pragma unroll
                for (int ct = 0; ct < 2; ct++){
                    int c = w*32 + ct*16 + l15;
                    float xm = acc_em[mt][ct][r] + bmv[ct];
                    float xg = acc_eg[mt][ct][r] + bgv[ct];
                    float gate = silu(xm)*sigm(xg);
                    float el = elbv[ct];
                    #pragma unroll
                    for (int rr = 0; rr < NRBF; rr++) el = fmaf(rbf_s[ml][rr], elwv[ct][rr], el);
                    float tbc = tbbv[ct];
                    #pragma unroll
                    for (int s = 0; s < SBF; s++) tbc = fmaf(tb_s[ml][s], tbgv[ct][s], tbc);
                    float enew = E[(size_t)e*UNITS + c] + tbc + gate*el;
                    E[(size_t)e*UNITS + c] = enew;
                    feat_s[ml*392 + 256 + c] = f2bf(enew);
                }
            }
        }
    }
    __syncthreads();

    // Phase 2: ga over K 256..383 (updated E)
    for (int ks = 8; ks < 12; ks++){
        short8 a0 = *(const short8*)(a0p + ks*32);
        short8 a1 = *(const short8*)(a1p + ks*32);
        #pragma unroll
        for (int ct = 0; ct < 2; ct++){
            int nt = w*2 + ct;
            size_t boff = ((size_t)(ks*8 + nt)*64 + lane)*8;
            short8 b_am = *(const short8*)(WamP + boff);
            short8 b_ag = *(const short8*)(WagP + boff);
            acc_am[0][ct] = __builtin_amdgcn_mfma_f32_16x16x32_bf16(a0, b_am, acc_am[0][ct], 0, 0, 0);
            acc_am[1][ct] = __builtin_amdgcn_mfma_f32_16x16x32_bf16(a1, b_am, acc_am[1][ct], 0, 0, 0);
            acc_ag[0][ct] = __builtin_amdgcn_mfma_f32_16x16x32_bf16(a0, b_ag, acc_ag[0][ct], 0, 0, 0);
            acc_ag[1][ct] = __builtin_amdgcn_mfma_f32_16x16x32_bf16(a1, b_ag, acc_ag[1][ct], 0, 0, 0);
        }
    }

    // Epilogue 2: atom scatter
    {
        float bmv[2], bgv[2], elbv[2], elwv[2][NRBF];
        #pragma unroll
        for (int ct = 0; ct < 2; ct++){
            int c = w*32 + ct*16 + l15;
            bmv[ct]  = bam[c];
            bgv[ct]  = bag[c];
            elbv[ct] = elab_[c];
            #pragma unroll
            for (int r = 0; r < NRBF; r++) elwv[ct][r] = elaw_[r*UNITS + c];
        }
        #pragma unroll
        for (int mt = 0; mt < 2; mt++){
            #pragma unroll
            for (int r = 0; r < 4; r++){
                int ml = mt*16 + quad*4 + r;
                int e  = e0 + ml;
                if (e >= NEDGE) continue;
                #pragma unroll
                for (int ct = 0; ct < 2; ct++){
                    int c = w*32 + ct*16 + l15;
                    float xm = acc_am[mt][ct][r] + bmv[ct];
                    float xg = acc_ag[mt][ct][r] + bgv[ct];
                    float gate = silu(xm)*sigm(xg);
                    float el = elbv[ct];
                    #pragma unroll
                    for (int rr = 0; rr < NRBF; rr++) el = fmaf(rbf_s[ml][rr], elwv[ct][rr], el);
                    atomicAdd(&agg[(size_t)src_s[ml]*UNITS + c], gate*el);
                }
            }
        }
    }
}

// ---------------- ghost expansion ----------------
__global__ void k_expand(const float* __restrict__ agg, const int* __restrict__ gmap,
                         float* __restrict__ A){
    int t = blockIdx.x*blockDim.x + threadIdx.x;
    if (t >= NTOTAL*32) return;
    int i = t >> 5, q = t & 31;
    int row = (i < NLOCAL) ? i : gmap[i - NLOCAL];
    ((float4*)A)[t] = ((const float4*)agg)[(size_t)row*32 + q];
}

// ---------------- final readout + global sum ----------------
__global__ void k_final(const float* __restrict__ A, const float* __restrict__ W1,
                        const float* __restrict__ b1, const float* __restrict__ W2,
                        const float* __restrict__ b2, const int* __restrict__ anum,
                        const float* __restrict__ escl, const float* __restrict__ eshf,
                        float* __restrict__ out){
    __shared__ float red[256];
    const int tid  = threadIdx.x;
    const int c    = tid & 127;
    const int half = tid >> 7;
    float b1c = b1[c];
    float w2c = W2[c];
    float b2v = b2[0];
    float tpart = 0.0f;
    const int npairs = NLOCAL/2;
    for (int p = blockIdx.x; p < npairs; p += gridDim.x){
        int a = 2*p + half;
        const float* h = A + (size_t)a*UNITS;
        float acc = b1c;
        for (int k = 0; k < UNITS; k++)
            acc = fmaf(h[k], W1[k*UNITS + c], acc);
        float hid = silu(acc);
        int z = anum[a];
        float sc = escl[z];
        tpart = fmaf(sc*hid, w2c, tpart);
        if (c == 0) tpart += sc*b2v + eshf[z];
    }
    red[tid] = tpart;
    __syncthreads();
    for (int s = 128; s > 0; s >>= 1){
        if (tid < s) red[tid] += red[tid + s];
        __syncthreads();
    }
    if (tid == 0) atomicAdd(out, red[0]);
}

extern "C" void kernel_launch(void* const* d_in, const int* in_sizes, int n_in,
                              void* d_out, int out_size, void* d_ws, size_t ws_size,
                              hipStream_t stream){
    const int*   anum  = (const int*)d_in[0];
    const float* pos   = (const float*)d_in[1];
    const float* cell  = (const float*)d_in[2];
    const float* pbc   = (const float*)d_in[3];
    const int*   esrc  = (const int*)d_in[4];
    const int*   edst  = (const int*)d_in[5];
    const int*   tbi   = (const int*)d_in[6];
    const int*   batch = (const int*)d_in[7];
    const int*   gmap  = (const int*)d_in[8];
    const float* embw  = (const float*)d_in[10];
    const float* encw  = (const float*)d_in[11];
    const float* encb  = (const float*)d_in[12];
    const float* tbaw  = (const float*)d_in[13];
    const float* tbab  = (const float*)d_in[14];
    const float* tbgw  = (const float*)d_in[15];
    const float* tbgb  = (const float*)d_in[16];
    const float* gewm  = (const float*)d_in[17];
    const float* gebm  = (const float*)d_in[18];
    const float* gewg  = (const float*)d_in[19];
    const float* gebg  = (const float*)d_in[20];
    const float* elew  = (const float*)d_in[21];
    const float* eleb  = (const float*)d_in[22];
    const float* gawm  = (const float*)d_in[23];
    const float* gabm  = (const float*)d_in[24];
    const float* gawg  = (const float*)d_in[25];
    const float* gabg  = (const float*)d_in[26];
    const float* elaw  = (const float*)d_in[27];
    const float* elab  = (const float*)d_in[28];
    const float* fw1   = (const float*)d_in[29];
    const float* fb1   = (const float*)d_in[30];
    const float* fw2   = (const float*)d_in[31];
    const float* fb2   = (const float*)d_in[32];
    const float* escl  = (const float*)d_in[33];
    const float* eshf  = (const float*)d_in[34];
    (void)in_sizes; (void)n_in; (void)out_size; (void)ws_size;

    float* ws    = (float*)d_ws;
    float* atomA = ws;                                   // NTOTAL*128
    float* agg   = atomA + (size_t)NTOTAL*UNITS;         // NLOCAL*128
    float* edgeE = agg   + (size_t)NLOCAL*UNITS;         // NEDGE*128
    float* evec  = edgeE + (size_t)NEDGE*UNITS;          // NEDGE*3
    float* elen  = evec  + (size_t)NEDGE*3;              // NEDGE
    float* rbf0  = elen  + (size_t)NEDGE;                // NEDGE*10
    float* tbout = rbf0  + (size_t)NEDGE*NRBF;           // NEDGE*9
    float* amlp  = tbout + (size_t)NEDGE*SBF;            // NLOCAL*9
    ushort* wpack = (ushort*)(amlp + (size_t)NLOCAL*SBF); // 3*4*49152 bf16

    float* out = (float*)d_out;
    hipMemsetAsync(out, 0, sizeof(float), stream);

    k_pack_w<<<(3*4*12*8*64 + 255)/256, 256, 0, stream>>>(gewm, gewg, gawm, gawg, wpack);
    k_edge_geom<<<(NEDGE+255)/256, 256, 0, stream>>>(pos, cell, pbc, esrc, edst, batch,
                                                     evec, elen, rbf0);
    k_embed<<<(NTOTAL*32+255)/256, 256, 0, stream>>>(anum, embw, atomA);
    k_edge_enc<<<(NEDGE*32+255)/256, 256, 0, stream>>>(rbf0, encw, encb, edgeE);

    const int gemm_blocks = (NEDGE+31)/32;
    for (int L = 0; L < NLAYERS; L++){
        const ushort* wpL = wpack + (size_t)L*4*49152;
        k_tb_mlp<<<(NLOCAL+255)/256, 256, 0, stream>>>(atomA,
            tbaw + (size_t)L*UNITS*SBF, tbab + (size_t)L*SBF, amlp);
        hipMemsetAsync(tbout, 0, (size_t)NEDGE*SBF*sizeof(float), stream);
        k_triple<<<(NTRIPLE+255)/256, 256, 0, stream>>>(evec, elen, esrc, tbi, amlp, tbout);
        hipMemcpyAsync(agg, atomA, (size_t)NLOCAL*UNITS*sizeof(float),
                       hipMemcpyDeviceToDevice, stream);
        k_gated_fused<<<gemm_blocks, 256, 0, stream>>>(atomA, edgeE, esrc, edst,
            tbout, tbgw + (size_t)L*SBF*UNITS, tbgb + (size_t)L*UNITS,
            wpL + 0*49152, wpL + 1*49152, wpL + 2*49152, wpL + 3*49152,
            gebm + (size_t)L*UNITS, gebg + (size_t)L*UNITS,
            elew + (size_t)L*NRBF*UNITS, eleb + (size_t)L*UNITS,
            gabm + (size_t)L*UNITS, gabg + (size_t)L*UNITS,
            elaw + (size_t)L*NRBF*UNITS, elab + (size_t)L*UNITS,
            rbf0, agg);
        if (L < NLAYERS-1)
            k_expand<<<(NTOTAL*32+255)/256, 256, 0, stream>>>(agg, gmap, atomA);
    }
    k_final<<<1024, 256, 0, stream>>>(agg, fw1, fb1, fw2, fb2, anum, escl, eshf, out);
}

// Round 6
// 1585.764 us; speedup vs baseline: 1.6140x; 1.6140x over previous
//
#include <hip/hip_runtime.h>
#include <math.h>

#define UNITS   128
#define NRBF    10
#define SBF     9
#define NLAYERS 3
#define NELEM   95
#define NTOTAL  60000
#define NLOCAL  50000
#define NGHOST  10000
#define NEDGE   250000
#define NTRIPLE 1000000
#define CUTOFF  5.0f
#define TBCUT   4.0f
#define PI_F    3.14159265358979323846f

typedef __attribute__((ext_vector_type(8))) short short8;
typedef __attribute__((ext_vector_type(4))) float f32x4;

// fast sigmoid/silu: v_exp_f32-based (__expf), ~1e-5 rel err — far below bf16 noise
__device__ __forceinline__ float sigm(float x){ return 1.0f/(1.0f+__expf(-x)); }
__device__ __forceinline__ float silu(float x){ return x/(1.0f+__expf(-x)); }
__device__ __forceinline__ float polycut(float r){
    float q = r*(1.0f/TBCUT);
    float q2 = q*q, q3 = q2*q;
    float p = 1.0f - 6.0f*q2*q3 + 15.0f*q2*q2 - 10.0f*q3;
    return (r <= TBCUT) ? p : 0.0f;
}
__device__ __forceinline__ ushort f2bf(float x){
    unsigned u = __float_as_uint(x);
    unsigned r = (u + 0x7fffu + ((u>>16)&1u)) >> 16;
    return (ushort)r;
}
__device__ __forceinline__ void fma4s(float4& acc, float s, const float4& v){
    acc.x = fmaf(s, v.x, acc.x);
    acc.y = fmaf(s, v.y, acc.y);
    acc.z = fmaf(s, v.z, acc.z);
    acc.w = fmaf(s, v.w, acc.w);
}

// ---------------- edge geometry + rbf ----------------
__global__ void k_edge_geom(const float* __restrict__ pos, const float* __restrict__ cell,
                            const float* __restrict__ pbc, const int* __restrict__ src,
                            const int* __restrict__ dst, const int* __restrict__ batch,
                            float* __restrict__ evec, float* __restrict__ elen,
                            float* __restrict__ rbf0){
    int e = blockIdx.x*blockDim.x + threadIdx.x;
    if (e >= NEDGE) return;
    int s = src[e], d = dst[e];
    int b = batch[s];
    const float* C = cell + b*9;
    float p0 = pbc[e*3+0], p1 = pbc[e*3+1], p2 = pbc[e*3+2];
    float vx = pos[s*3+0] - (pos[d*3+0] + p0*C[0] + p1*C[3] + p2*C[6]);
    float vy = pos[s*3+1] - (pos[d*3+1] + p0*C[1] + p1*C[4] + p2*C[7]);
    float vz = pos[s*3+2] - (pos[d*3+2] + p0*C[2] + p1*C[5] + p2*C[8]);
    float r = sqrtf(vx*vx + vy*vy + vz*vz);
    evec[e*3+0] = vx; evec[e*3+1] = vy; evec[e*3+2] = vz;
    elen[e] = r;
    #pragma unroll
    for (int i = 0; i < NRBF; i++){
        float mu = (CUTOFF/(NRBF-1))*i;
        float dm = r - mu;
        rbf0[e*NRBF + i] = __expf(-dm*dm*2.0f);
    }
}

// ---------------- atom embedding gather ----------------
__global__ void k_embed(const int* __restrict__ anum, const float* __restrict__ embw,
                        float* __restrict__ A){
    int t = blockIdx.x*blockDim.x + threadIdx.x;
    if (t >= NTOTAL*32) return;
    int a = t >> 5, q = t & 31;
    ((float4*)A)[t] = ((const float4*)embw)[anum[a]*32 + q];
}

// ---------------- edge encoding: E = rbf0 @ Wenc + benc ----------------
__global__ void k_edge_enc(const float* __restrict__ rbf0, const float* __restrict__ encw,
                           const float* __restrict__ encb, float* __restrict__ E){
    int t = blockIdx.x*blockDim.x + threadIdx.x;
    if (t >= NEDGE*32) return;
    int e = t >> 5, q = t & 31;
    float4 acc = ((const float4*)encb)[q];
    const float4* W4 = (const float4*)encw;
    #pragma unroll
    for (int r = 0; r < NRBF; r++){
        float rv = rbf0[e*NRBF + r];
        fma4s(acc, rv, W4[r*32 + q]);
    }
    ((float4*)E)[t] = acc;
}

// ---------------- pack gated-MLP weights into MFMA B-fragment layout ----------------
// layout: [L][mat(ge_m,ge_g,ga_m,ga_g)][kb:12][nt:8][lane:64][j:8] bf16
__global__ void k_pack_w(const float* __restrict__ gewm, const float* __restrict__ gewg,
                         const float* __restrict__ gawm, const float* __restrict__ gawg,
                         ushort* __restrict__ wp){
    int t = blockIdx.x*blockDim.x + threadIdx.x;
    if (t >= 3*4*12*8*64) return;
    int lane = t & 63;
    int nt   = (t>>6) & 7;
    int rest = t >> 9;
    int kb   = rest % 12;
    int r2   = rest / 12;
    int mat  = r2 & 3;
    int L    = r2 >> 2;
    const float* src;
    if      (mat == 0) src = gewm;
    else if (mat == 1) src = gewg;
    else if (mat == 2) src = gawm;
    else               src = gawg;
    src += (size_t)L*384*128;
    int n = nt*16 + (lane & 15);
    int kbase = kb*32 + (lane>>4)*8;
    ushort* dst = wp + (size_t)t*8;
    #pragma unroll
    for (int j = 0; j < 8; j++) dst[j] = f2bf(src[(size_t)(kbase+j)*128 + n]);
}

// ---------------- per-layer: atom sbf mlp ----------------
__global__ void k_tb_mlp(const float* __restrict__ A, const float* __restrict__ W,
                         const float* __restrict__ b, float* __restrict__ out){
    int a = blockIdx.x*blockDim.x + threadIdx.x;
    if (a >= NLOCAL) return;
    float acc[SBF];
    #pragma unroll
    for (int s = 0; s < SBF; s++) acc[s] = b[s];
    const float4* row4 = (const float4*)(A + (size_t)a*UNITS);
    for (int k4 = 0; k4 < 32; k4++){
        float4 v = row4[k4];
        const float* w = W + (k4*4)*SBF;
        #pragma unroll
        for (int s = 0; s < SBF; s++){
            acc[s] = fmaf(v.x, w[s],        acc[s]);
            acc[s] = fmaf(v.y, w[s+SBF],    acc[s]);
            acc[s] = fmaf(v.z, w[s+2*SBF],  acc[s]);
            acc[s] = fmaf(v.w, w[s+3*SBF],  acc[s]);
        }
    }
    #pragma unroll
    for (int s = 0; s < SBF; s++) out[a*SBF + s] = sigm(acc[s]);
}

// ---------------- per-layer: triples -> scatter into tb_out ----------------
__global__ void k_triple(const float* __restrict__ evec, const float* __restrict__ elen,
                         const int* __restrict__ esrc, const int* __restrict__ tbi,
                         const float* __restrict__ amlp, float* __restrict__ tb_out){
    int t = blockIdx.x*blockDim.x + threadIdx.x;
    if (t >= NTRIPLE) return;
    int ij = tbi[2*t], ik = tbi[2*t+1];
    float rij = elen[ij], rik = elen[ik];
    float cutij = polycut(rij), cutik = polycut(rik);
    float cc = cutij*cutik;
    if (cc == 0.0f) return;
    float ax = evec[ij*3+0], ay = evec[ij*3+1], az = evec[ij*3+2];
    float bx = evec[ik*3+0], by = evec[ik*3+1], bz = evec[ik*3+2];
    float dot = ax*bx + ay*by + az*bz;
    float c = dot/(rij*rik + 1e-12f);
    c = fminf(fmaxf(c, -1.0f + 1e-7f), 1.0f - 1e-7f);
    float a0 = 1.0f, a1 = c, a2 = 2.0f*c*c - 1.0f;
    float x = rik*(PI_F/TBCUT);
    float s1, c1;
    sincosf(x, &s1, &c1);
    float s2 = 2.0f*s1*c1;
    float s3 = s1*(3.0f - 4.0f*s1*s1);
    float inv = 1.0f/(rik + 1e-6f);
    float r0 = s1*inv, r1 = s2*inv, r2 = s3*inv;
    int ka = esrc[ik];
    const float* am = amlp + (size_t)ka*SBF;
    float* dst = tb_out + (size_t)ij*SBF;
    atomicAdd(dst+0, r0*a0*am[0]*cc);
    atomicAdd(dst+1, r0*a1*am[1]*cc);
    atomicAdd(dst+2, r0*a2*am[2]*cc);
    atomicAdd(dst+3, r1*a0*am[3]*cc);
    atomicAdd(dst+4, r1*a1*am[4]*cc);
    atomicAdd(dst+5, r1*a2*am[5]*cc);
    atomicAdd(dst+6, r2*a0*am[6]*cc);
    atomicAdd(dst+7, r2*a1*am[7]*cc);
    atomicAdd(dst+8, r2*a2*am[8]*cc);
}

// ---------------- fused per-layer gated blocks (ge + ga) via bf16 MFMA ----------------
// 32 edges/block, 4 waves. feat = [A[src] | A[dst] | E+tbgate] bf16 in LDS (stride 392).
// Phase 1: full-K ge GEMM + A-part (K 0..255) of ga GEMM in one loop.
// Epilogue 1: E_new = E_old + tbgate_f32 + silu(m)sigm(g)*el_e ; write global E + LDS bf16.
// Phase 2: remaining K 256..383 of ga GEMM on E_new.
// Epilogue 2: agg[src] += silu(m)sigm(g)*el_a (device atomics).
// launch_bounds(256,4): VGPR 64, no spill. (256,5) forced VGPR->48 and spilled to
// scratch: FETCH 359->670MB, WRITE 437MB->1.3GB, dispatch 387->700us. Do not raise.
__global__ __launch_bounds__(256, 4)
void k_gated_fused(const float* __restrict__ A, float* __restrict__ E,
                   const int* __restrict__ esrc, const int* __restrict__ edst,
                   const float* __restrict__ tb_out, const float* __restrict__ tbg,
                   const float* __restrict__ tbb,
                   const ushort* __restrict__ WemP, const ushort* __restrict__ WegP,
                   const ushort* __restrict__ WamP, const ushort* __restrict__ WagP,
                   const float* __restrict__ bem, const float* __restrict__ beg,
                   const float* __restrict__ elew_, const float* __restrict__ eleb_,
                   const float* __restrict__ bam, const float* __restrict__ bag,
                   const float* __restrict__ elaw_, const float* __restrict__ elab_,
                   const float* __restrict__ rbf0, float* __restrict__ agg){
    __shared__ __align__(16) ushort feat_s[32*392];
    __shared__ float rbf_s[32][NRBF];
    __shared__ float tb_s[32][SBF];
    __shared__ int   src_s[32];
    __shared__ int   dst_s[32];

    const int tid = threadIdx.x;
    const int e0  = blockIdx.x*32;

    if (tid < 32){
        int e = min(e0 + tid, NEDGE-1);
        src_s[tid] = esrc[e];
        dst_s[tid] = edst[e];
        #pragma unroll
        for (int r = 0; r < NRBF; r++) rbf_s[tid][r] = rbf0[(size_t)e*NRBF + r];
        #pragma unroll
        for (int s = 0; s < SBF; s++) tb_s[tid][s] = tb_out[(size_t)e*SBF + s];
    }
    __syncthreads();

    const float4* A4   = (const float4*)A;
    const float4* E4   = (const float4*)E;
    const float4* tbg4 = (const float4*)tbg;
    const float4* tbb4 = (const float4*)tbb;

    // stage feat: 32 rows x 96 float4 -> bf16, 12 pieces/thread
    #pragma unroll
    for (int j = 0; j < 12; j++){
        int idx = j*256 + tid;
        int m   = idx/96;
        int k4  = idx - m*96;
        float4 v;
        if (k4 < 32){
            v = A4[(size_t)src_s[m]*32 + k4];
        } else if (k4 < 64){
            v = A4[(size_t)dst_s[m]*32 + (k4-32)];
        } else {
            int q = k4 - 64;
            int e = min(e0 + m, NEDGE-1);
            v = E4[(size_t)e*32 + q];
            float4 tacc = tbb4[q];
            #pragma unroll
            for (int s = 0; s < SBF; s++) fma4s(tacc, tb_s[m][s], tbg4[s*32 + q]);
            v.x += tacc.x; v.y += tacc.y; v.z += tacc.z; v.w += tacc.w;
        }
        ushort4 h;
        h.x = f2bf(v.x); h.y = f2bf(v.y); h.z = f2bf(v.z); h.w = f2bf(v.w);
        *(ushort4*)&feat_s[m*392 + k4*4] = h;
    }
    __syncthreads();

    const int lane = tid & 63;
    const int w    = tid >> 6;
    const int quad = lane >> 4;
    const int l15  = lane & 15;

    f32x4 zero4 = {0.f, 0.f, 0.f, 0.f};
    f32x4 acc_em[2][2], acc_eg[2][2], acc_am[2][2], acc_ag[2][2];
    #pragma unroll
    for (int mt = 0; mt < 2; mt++)
        #pragma unroll
        for (int ct = 0; ct < 2; ct++){
            acc_em[mt][ct] = zero4; acc_eg[mt][ct] = zero4;
            acc_am[mt][ct] = zero4; acc_ag[mt][ct] = zero4;
        }

    const ushort* a0p = feat_s + l15*392 + quad*8;
    const ushort* a1p = a0p + 16*392;

    // Phase 1: ge over K 0..383; ga over K 0..255 (A-part only)
    for (int ks = 0; ks < 12; ks++){
        short8 a0 = *(const short8*)(a0p + ks*32);
        short8 a1 = *(const short8*)(a1p + ks*32);
        #pragma unroll
        for (int ct = 0; ct < 2; ct++){
            int nt = w*2 + ct;
            size_t boff = ((size_t)(ks*8 + nt)*64 + lane)*8;
            short8 b_em = *(const short8*)(WemP + boff);
            short8 b_eg = *(const short8*)(WegP + boff);
            acc_em[0][ct] = __builtin_amdgcn_mfma_f32_16x16x32_bf16(a0, b_em, acc_em[0][ct], 0, 0, 0);
            acc_em[1][ct] = __builtin_amdgcn_mfma_f32_16x16x32_bf16(a1, b_em, acc_em[1][ct], 0, 0, 0);
            acc_eg[0][ct] = __builtin_amdgcn_mfma_f32_16x16x32_bf16(a0, b_eg, acc_eg[0][ct], 0, 0, 0);
            acc_eg[1][ct] = __builtin_amdgcn_mfma_f32_16x16x32_bf16(a1, b_eg, acc_eg[1][ct], 0, 0, 0);
            if (ks < 8){
                short8 b_am = *(const short8*)(WamP + boff);
                short8 b_ag = *(const short8*)(WagP + boff);
                acc_am[0][ct] = __builtin_amdgcn_mfma_f32_16x16x32_bf16(a0, b_am, acc_am[0][ct], 0, 0, 0);
                acc_am[1][ct] = __builtin_amdgcn_mfma_f32_16x16x32_bf16(a1, b_am, acc_am[1][ct], 0, 0, 0);
                acc_ag[0][ct] = __builtin_amdgcn_mfma_f32_16x16x32_bf16(a0, b_ag, acc_ag[0][ct], 0, 0, 0);
                acc_ag[1][ct] = __builtin_amdgcn_mfma_f32_16x16x32_bf16(a1, b_ag, acc_ag[1][ct], 0, 0, 0);
            }
        }
    }

    // Epilogue 1: edge update
    {
        float bmv[2], bgv[2], elbv[2], elwv[2][NRBF], tbbv[2], tbgv[2][SBF];
        #pragma unroll
        for (int ct = 0; ct < 2; ct++){
            int c = w*32 + ct*16 + l15;
            bmv[ct]  = bem[c];
            bgv[ct]  = beg[c];
            elbv[ct] = eleb_[c];
            #pragma unroll
            for (int r = 0; r < NRBF; r++) elwv[ct][r] = elew_[r*UNITS + c];
            tbbv[ct] = tbb[c];
            #pragma unroll
            for (int s = 0; s < SBF; s++) tbgv[ct][s] = tbg[s*UNITS + c];
        }
        // all phase-1 LDS reads are done (loop above); safe to overwrite E-region after barrier
        __syncthreads();
        #pragma unroll
        for (int mt = 0; mt < 2; mt++){
            #pragma unroll
            for (int r = 0; r < 4; r++){
                int ml = mt*16 + quad*4 + r;
                int e  = e0 + ml;
                if (e >= NEDGE) continue;
                #pragma unroll
                for (int ct = 0; ct < 2; ct++){
                    int c = w*32 + ct*16 + l15;
                    float xm = acc_em[mt][ct][r] + bmv[ct];
                    float xg = acc_eg[mt][ct][r] + bgv[ct];
                    float gate = silu(xm)*sigm(xg);
                    float el = elbv[ct];
                    #pragma unroll
                    for (int rr = 0; rr < NRBF; rr++) el = fmaf(rbf_s[ml][rr], elwv[ct][rr], el);
                    float tbc = tbbv[ct];
                    #pragma unroll
                    for (int s = 0; s < SBF; s++) tbc = fmaf(tb_s[ml][s], tbgv[ct][s], tbc);
                    float enew = E[(size_t)e*UNITS + c] + tbc + gate*el;
                    E[(size_t)e*UNITS + c] = enew;
                    feat_s[ml*392 + 256 + c] = f2bf(enew);
                }
            }
        }
    }
    __syncthreads();

    // Phase 2: ga over K 256..383 (updated E)
    for (int ks = 8; ks < 12; ks++){
        short8 a0 = *(const short8*)(a0p + ks*32);
        short8 a1 = *(const short8*)(a1p + ks*32);
        #pragma unroll
        for (int ct = 0; ct < 2; ct++){
            int nt = w*2 + ct;
            size_t boff = ((size_t)(ks*8 + nt)*64 + lane)*8;
            short8 b_am = *(const short8*)(WamP + boff);
            short8 b_ag = *(const short8*)(WagP + boff);
            acc_am[0][ct] = __builtin_amdgcn_mfma_f32_16x16x32_bf16(a0, b_am, acc_am[0][ct], 0, 0, 0);
            acc_am[1][ct] = __builtin_amdgcn_mfma_f32_16x16x32_bf16(a1, b_am, acc_am[1][ct], 0, 0, 0);
            acc_ag[0][ct] = __builtin_amdgcn_mfma_f32_16x16x32_bf16(a0, b_ag, acc_ag[0][ct], 0, 0, 0);
            acc_ag[1][ct] = __builtin_amdgcn_mfma_f32_16x16x32_bf16(a1, b_ag, acc_ag[1][ct], 0, 0, 0);
        }
    }

    // Epilogue 2: atom scatter
    {
        float bmv[2], bgv[2], elbv[2], elwv[2][NRBF];
        #pragma unroll
        for (int ct = 0; ct < 2; ct++){
            int c = w*32 + ct*16 + l15;
            bmv[ct]  = bam[c];
            bgv[ct]  = bag[c];
            elbv[ct] = elab_[c];
            #pragma unroll
            for (int r = 0; r < NRBF; r++) elwv[ct][r] = elaw_[r*UNITS + c];
        }
        #pragma unroll
        for (int mt = 0; mt < 2; mt++){
            #pragma unroll
            for (int r = 0; r < 4; r++){
                int ml = mt*16 + quad*4 + r;
                int e  = e0 + ml;
                if (e >= NEDGE) continue;
                #pragma unroll
                for (int ct = 0; ct < 2; ct++){
                    int c = w*32 + ct*16 + l15;
                    float xm = acc_am[mt][ct][r] + bmv[ct];
                    float xg = acc_ag[mt][ct][r] + bgv[ct];
                    float gate = silu(xm)*sigm(xg);
                    float el = elbv[ct];
                    #pragma unroll
                    for (int rr = 0; rr < NRBF; rr++) el = fmaf(rbf_s[ml][rr], elwv[ct][rr], el);
                    atomicAdd(&agg[(size_t)src_s[ml]*UNITS + c], gate*el);
                }
            }
        }
    }
}

// ---------------- ghost expansion ----------------
__global__ void k_expand(const float* __restrict__ agg, const int* __restrict__ gmap,
                         float* __restrict__ A){
    int t = blockIdx.x*blockDim.x + threadIdx.x;
    if (t >= NTOTAL*32) return;
    int i = t >> 5, q = t & 31;
    int row = (i < NLOCAL) ? i : gmap[i - NLOCAL];
    ((float4*)A)[t] = ((const float4*)agg)[(size_t)row*32 + q];
}

// ---------------- final readout + global sum ----------------
__global__ void k_final(const float* __restrict__ A, const float* __restrict__ W1,
                        const float* __restrict__ b1, const float* __restrict__ W2,
                        const float* __restrict__ b2, const int* __restrict__ anum,
                        const float* __restrict__ escl, const float* __restrict__ eshf,
                        float* __restrict__ out){
    __shared__ float red[256];
    const int tid  = threadIdx.x;
    const int c    = tid & 127;
    const int half = tid >> 7;
    float b1c = b1[c];
    float w2c = W2[c];
    float b2v = b2[0];
    float tpart = 0.0f;
    const int npairs = NLOCAL/2;
    for (int p = blockIdx.x; p < npairs; p += gridDim.x){
        int a = 2*p + half;
        const float* h = A + (size_t)a*UNITS;
        float acc = b1c;
        for (int k = 0; k < UNITS; k++)
            acc = fmaf(h[k], W1[k*UNITS + c], acc);
        float hid = silu(acc);
        int z = anum[a];
        float sc = escl[z];
        tpart = fmaf(sc*hid, w2c, tpart);
        if (c == 0) tpart += sc*b2v + eshf[z];
    }
    red[tid] = tpart;
    __syncthreads();
    for (int s = 128; s > 0; s >>= 1){
        if (tid < s) red[tid] += red[tid + s];
        __syncthreads();
    }
    if (tid == 0) atomicAdd(out, red[0]);
}

extern "C" void kernel_launch(void* const* d_in, const int* in_sizes, int n_in,
                              void* d_out, int out_size, void* d_ws, size_t ws_size,
                              hipStream_t stream){
    const int*   anum  = (const int*)d_in[0];
    const float* pos   = (const float*)d_in[1];
    const float* cell  = (const float*)d_in[2];
    const float* pbc   = (const float*)d_in[3];
    const int*   esrc  = (const int*)d_in[4];
    const int*   edst  = (const int*)d_in[5];
    const int*   tbi   = (const int*)d_in[6];
    const int*   batch = (const int*)d_in[7];
    const int*   gmap  = (const int*)d_in[8];
    const float* embw  = (const float*)d_in[10];
    const float* encw  = (const float*)d_in[11];
    const float* encb  = (const float*)d_in[12];
    const float* tbaw  = (const float*)d_in[13];
    const float* tbab  = (const float*)d_in[14];
    const float* tbgw  = (const float*)d_in[15];
    const float* tbgb  = (const float*)d_in[16];
    const float* gewm  = (const float*)d_in[17];
    const float* gebm  = (const float*)d_in[18];
    const float* gewg  = (const float*)d_in[19];
    const float* gebg  = (const float*)d_in[20];
    const float* elew  = (const float*)d_in[21];
    const float* eleb  = (const float*)d_in[22];
    const float* gawm  = (const float*)d_in[23];
    const float* gabm  = (const float*)d_in[24];
    const float* gawg  = (const float*)d_in[25];
    const float* gabg  = (const float*)d_in[26];
    const float* elaw  = (const float*)d_in[27];
    const float* elab  = (const float*)d_in[28];
    const float* fw1   = (const float*)d_in[29];
    const float* fb1   = (const float*)d_in[30];
    const float* fw2   = (const float*)d_in[31];
    const float* fb2   = (const float*)d_in[32];
    const float* escl  = (const float*)d_in[33];
    const float* eshf  = (const float*)d_in[34];
    (void)in_sizes; (void)n_in; (void)out_size; (void)ws_size;

    float* ws    = (float*)d_ws;
    float* atomA = ws;                                   // NTOTAL*128
    float* agg   = atomA + (size_t)NTOTAL*UNITS;         // NLOCAL*128
    float* edgeE = agg   + (size_t)NLOCAL*UNITS;         // NEDGE*128
    float* evec  = edgeE + (size_t)NEDGE*UNITS;          // NEDGE*3
    float* elen  = evec  + (size_t)NEDGE*3;              // NEDGE
    float* rbf0  = elen  + (size_t)NEDGE;                // NEDGE*10
    float* tbout = rbf0  + (size_t)NEDGE*NRBF;           // NEDGE*9
    float* amlp  = tbout + (size_t)NEDGE*SBF;            // NLOCAL*9
    ushort* wpack = (ushort*)(amlp + (size_t)NLOCAL*SBF); // 3*4*49152 bf16

    float* out = (float*)d_out;
    hipMemsetAsync(out, 0, sizeof(float), stream);

    k_pack_w<<<(3*4*12*8*64 + 255)/256, 256, 0, stream>>>(gewm, gewg, gawm, gawg, wpack);
    k_edge_geom<<<(NEDGE+255)/256, 256, 0, stream>>>(pos, cell, pbc, esrc, edst, batch,
                                                     evec, elen, rbf0);
    k_embed<<<(NTOTAL*32+255)/256, 256, 0, stream>>>(anum, embw, atomA);
    k_edge_enc<<<(NEDGE*32+255)/256, 256, 0, stream>>>(rbf0, encw, encb, edgeE);

    const int gemm_blocks = (NEDGE+31)/32;
    for (int L = 0; L < NLAYERS; L++){
        const ushort* wpL = wpack + (size_t)L*4*49152;
        k_tb_mlp<<<(NLOCAL+255)/256, 256, 0, stream>>>(atomA,
            tbaw + (size_t)L*UNITS*SBF, tbab + (size_t)L*SBF, amlp);
        hipMemsetAsync(tbout, 0, (size_t)NEDGE*SBF*sizeof(float), stream);
        k_triple<<<(NTRIPLE+255)/256, 256, 0, stream>>>(evec, elen, esrc, tbi, amlp, tbout);
        hipMemcpyAsync(agg, atomA, (size_t)NLOCAL*UNITS*sizeof(float),
                       hipMemcpyDeviceToDevice, stream);
        k_gated_fused<<<gemm_blocks, 256, 0, stream>>>(atomA, edgeE, esrc, edst,
            tbout, tbgw + (size_t)L*SBF*UNITS, tbgb + (size_t)L*UNITS,
            wpL + 0*49152, wpL + 1*49152, wpL + 2*49152, wpL + 3*49152,
            gebm + (size_t)L*UNITS, gebg + (size_t)L*UNITS,
            elew + (size_t)L*NRBF*UNITS, eleb + (size_t)L*UNITS,
            gabm + (size_t)L*UNITS, gabg + (size_t)L*UNITS,
            elaw + (size_t)L*NRBF*UNITS, elab + (size_t)L*UNITS,
            rbf0, agg);
        if (L < NLAYERS-1)
            k_expand<<<(NTOTAL*32+255)/256, 256, 0, stream>>>(agg, gmap, atomA);
    }
    k_final<<<1024, 256, 0, stream>>>(agg, fw1, fb1, fw2, fb2, anum, escl, eshf, out);
}

// Round 7
// 1568.864 us; speedup vs baseline: 1.6314x; 1.0108x over previous
//
#include <hip/hip_runtime.h>
#include <math.h>

#define UNITS   128
#define NRBF    10
#define SBF     9
#define NLAYERS 3
#define NELEM   95
#define NTOTAL  60000
#define NLOCAL  50000
#define NGHOST  10000
#define NEDGE   250000
#define NTRIPLE 1000000
#define CUTOFF  5.0f
#define TBCUT   4.0f
#define PI_F    3.14159265358979323846f

typedef __attribute__((ext_vector_type(8))) short short8;
typedef __attribute__((ext_vector_type(4))) float f32x4;

// fast sigmoid/silu: v_exp_f32-based (__expf), ~1e-5 rel err — far below bf16 noise
__device__ __forceinline__ float sigm(float x){ return 1.0f/(1.0f+__expf(-x)); }
__device__ __forceinline__ float silu(float x){ return x/(1.0f+__expf(-x)); }
__device__ __forceinline__ float polycut(float r){
    float q = r*(1.0f/TBCUT);
    float q2 = q*q, q3 = q2*q;
    float p = 1.0f - 6.0f*q2*q3 + 15.0f*q2*q2 - 10.0f*q3;
    return (r <= TBCUT) ? p : 0.0f;
}
__device__ __forceinline__ ushort f2bf(float x){
    unsigned u = __float_as_uint(x);
    unsigned r = (u + 0x7fffu + ((u>>16)&1u)) >> 16;
    return (ushort)r;
}
__device__ __forceinline__ float bf2f(ushort h){
    return __uint_as_float(((unsigned)h) << 16);
}
__device__ __forceinline__ void fma4s(float4& acc, float s, const float4& v){
    acc.x = fmaf(s, v.x, acc.x);
    acc.y = fmaf(s, v.y, acc.y);
    acc.z = fmaf(s, v.z, acc.z);
    acc.w = fmaf(s, v.w, acc.w);
}

// ---------------- edge geometry + rbf ----------------
__global__ void k_edge_geom(const float* __restrict__ pos, const float* __restrict__ cell,
                            const float* __restrict__ pbc, const int* __restrict__ src,
                            const int* __restrict__ dst, const int* __restrict__ batch,
                            float* __restrict__ evec, float* __restrict__ elen,
                            float* __restrict__ rbf0){
    int e = blockIdx.x*blockDim.x + threadIdx.x;
    if (e >= NEDGE) return;
    int s = src[e], d = dst[e];
    int b = batch[s];
    const float* C = cell + b*9;
    float p0 = pbc[e*3+0], p1 = pbc[e*3+1], p2 = pbc[e*3+2];
    float vx = pos[s*3+0] - (pos[d*3+0] + p0*C[0] + p1*C[3] + p2*C[6]);
    float vy = pos[s*3+1] - (pos[d*3+1] + p0*C[1] + p1*C[4] + p2*C[7]);
    float vz = pos[s*3+2] - (pos[d*3+2] + p0*C[2] + p1*C[5] + p2*C[8]);
    float r = sqrtf(vx*vx + vy*vy + vz*vz);
    evec[e*3+0] = vx; evec[e*3+1] = vy; evec[e*3+2] = vz;
    elen[e] = r;
    #pragma unroll
    for (int i = 0; i < NRBF; i++){
        float mu = (CUTOFF/(NRBF-1))*i;
        float dm = r - mu;
        rbf0[e*NRBF + i] = __expf(-dm*dm*2.0f);
    }
}

// ---------------- atom embedding gather (f32 + bf16 mirror) ----------------
__global__ void k_embed(const int* __restrict__ anum, const float* __restrict__ embw,
                        float* __restrict__ A, ushort* __restrict__ Ah){
    int t = blockIdx.x*blockDim.x + threadIdx.x;
    if (t >= NTOTAL*32) return;
    int a = t >> 5, q = t & 31;
    float4 v = ((const float4*)embw)[anum[a]*32 + q];
    ((float4*)A)[t] = v;
    ushort4 h;
    h.x = f2bf(v.x); h.y = f2bf(v.y); h.z = f2bf(v.z); h.w = f2bf(v.w);
    ((ushort4*)Ah)[t] = h;
}

// ---------------- edge encoding: Eh = bf16(rbf0 @ Wenc + benc) ----------------
__global__ void k_edge_enc(const float* __restrict__ rbf0, const float* __restrict__ encw,
                           const float* __restrict__ encb, ushort* __restrict__ Eh){
    int t = blockIdx.x*blockDim.x + threadIdx.x;
    if (t >= NEDGE*32) return;
    int e = t >> 5, q = t & 31;
    float4 acc = ((const float4*)encb)[q];
    const float4* W4 = (const float4*)encw;
    #pragma unroll
    for (int r = 0; r < NRBF; r++){
        float rv = rbf0[e*NRBF + r];
        fma4s(acc, rv, W4[r*32 + q]);
    }
    ushort4 h;
    h.x = f2bf(acc.x); h.y = f2bf(acc.y); h.z = f2bf(acc.z); h.w = f2bf(acc.w);
    ((ushort4*)Eh)[t] = h;
}

// ---------------- pack gated-MLP weights into MFMA B-fragment layout ----------------
// layout: [L][mat(ge_m,ge_g,ga_m,ga_g)][kb:12][nt:8][lane:64][j:8] bf16
__global__ void k_pack_w(const float* __restrict__ gewm, const float* __restrict__ gewg,
                         const float* __restrict__ gawm, const float* __restrict__ gawg,
                         ushort* __restrict__ wp){
    int t = blockIdx.x*blockDim.x + threadIdx.x;
    if (t >= 3*4*12*8*64) return;
    int lane = t & 63;
    int nt   = (t>>6) & 7;
    int rest = t >> 9;
    int kb   = rest % 12;
    int r2   = rest / 12;
    int mat  = r2 & 3;
    int L    = r2 >> 2;
    const float* src;
    if      (mat == 0) src = gewm;
    else if (mat == 1) src = gewg;
    else if (mat == 2) src = gawm;
    else               src = gawg;
    src += (size_t)L*384*128;
    int n = nt*16 + (lane & 15);
    int kbase = kb*32 + (lane>>4)*8;
    ushort* dst = wp + (size_t)t*8;
    #pragma unroll
    for (int j = 0; j < 8; j++) dst[j] = f2bf(src[(size_t)(kbase+j)*128 + n]);
}

// ---------------- per-layer: atom sbf mlp ----------------
__global__ void k_tb_mlp(const float* __restrict__ A, const float* __restrict__ W,
                         const float* __restrict__ b, float* __restrict__ out){
    int a = blockIdx.x*blockDim.x + threadIdx.x;
    if (a >= NLOCAL) return;
    float acc[SBF];
    #pragma unroll
    for (int s = 0; s < SBF; s++) acc[s] = b[s];
    const float4* row4 = (const float4*)(A + (size_t)a*UNITS);
    for (int k4 = 0; k4 < 32; k4++){
        float4 v = row4[k4];
        const float* w = W + (k4*4)*SBF;
        #pragma unroll
        for (int s = 0; s < SBF; s++){
            acc[s] = fmaf(v.x, w[s],        acc[s]);
            acc[s] = fmaf(v.y, w[s+SBF],    acc[s]);
            acc[s] = fmaf(v.z, w[s+2*SBF],  acc[s]);
            acc[s] = fmaf(v.w, w[s+3*SBF],  acc[s]);
        }
    }
    #pragma unroll
    for (int s = 0; s < SBF; s++) out[a*SBF + s] = sigm(acc[s]);
}

// ---------------- per-layer: triples -> scatter into tb_out ----------------
__global__ void k_triple(const float* __restrict__ evec, const float* __restrict__ elen,
                         const int* __restrict__ esrc, const int* __restrict__ tbi,
                         const float* __restrict__ amlp, float* __restrict__ tb_out){
    int t = blockIdx.x*blockDim.x + threadIdx.x;
    if (t >= NTRIPLE) return;
    int ij = tbi[2*t], ik = tbi[2*t+1];
    float rij = elen[ij], rik = elen[ik];
    float cutij = polycut(rij), cutik = polycut(rik);
    float cc = cutij*cutik;
    if (cc == 0.0f) return;
    float ax = evec[ij*3+0], ay = evec[ij*3+1], az = evec[ij*3+2];
    float bx = evec[ik*3+0], by = evec[ik*3+1], bz = evec[ik*3+2];
    float dot = ax*bx + ay*by + az*bz;
    float c = dot/(rij*rik + 1e-12f);
    c = fminf(fmaxf(c, -1.0f + 1e-7f), 1.0f - 1e-7f);
    float a0 = 1.0f, a1 = c, a2 = 2.0f*c*c - 1.0f;
    float x = rik*(PI_F/TBCUT);
    float s1, c1;
    sincosf(x, &s1, &c1);
    float s2 = 2.0f*s1*c1;
    float s3 = s1*(3.0f - 4.0f*s1*s1);
    float inv = 1.0f/(rik + 1e-6f);
    float r0 = s1*inv, r1 = s2*inv, r2 = s3*inv;
    int ka = esrc[ik];
    const float* am = amlp + (size_t)ka*SBF;
    float* dst = tb_out + (size_t)ij*SBF;
    atomicAdd(dst+0, r0*a0*am[0]*cc);
    atomicAdd(dst+1, r0*a1*am[1]*cc);
    atomicAdd(dst+2, r0*a2*am[2]*cc);
    atomicAdd(dst+3, r1*a0*am[3]*cc);
    atomicAdd(dst+4, r1*a1*am[4]*cc);
    atomicAdd(dst+5, r1*a2*am[5]*cc);
    atomicAdd(dst+6, r2*a0*am[6]*cc);
    atomicAdd(dst+7, r2*a1*am[7]*cc);
    atomicAdd(dst+8, r2*a2*am[8]*cc);
}

// ---------------- fused per-layer gated blocks (ge + ga) via bf16 MFMA ----------------
// All GEMM-side tensors stored bf16 (Ah, Eh): halves the gather/stream traffic.
// 32 edges/block, 4 waves. feat = [Ah[src] | Ah[dst] | Eh+tbgate] bf16 in LDS (stride 392).
// Phase 1: full-K ge GEMM + A-part (K 0..255) of ga GEMM in one loop.
// Epilogue 1: E_new = E_old + tbgate_f32 + silu(m)sigm(g)*el_e ; write Eh + LDS bf16.
// Phase 2: remaining K 256..383 of ga GEMM on E_new.
// Epilogue 2: agg[src] += silu(m)sigm(g)*el_a (device atomics, f32).
// launch_bounds(256,4): VGPR 64, no spill. (256,5) forced VGPR->48 and spilled to
// scratch: FETCH 359->670MB, WRITE 437MB->1.3GB, dispatch 387->700us. Do not raise.
__global__ __launch_bounds__(256, 4)
void k_gated_fused(const ushort* __restrict__ Ah, ushort* __restrict__ Eh,
                   const int* __restrict__ esrc, const int* __restrict__ edst,
                   const float* __restrict__ tb_out, const float* __restrict__ tbg,
                   const float* __restrict__ tbb,
                   const ushort* __restrict__ WemP, const ushort* __restrict__ WegP,
                   const ushort* __restrict__ WamP, const ushort* __restrict__ WagP,
                   const float* __restrict__ bem, const float* __restrict__ beg,
                   const float* __restrict__ elew_, const float* __restrict__ eleb_,
                   const float* __restrict__ bam, const float* __restrict__ bag,
                   const float* __restrict__ elaw_, const float* __restrict__ elab_,
                   const float* __restrict__ rbf0, float* __restrict__ agg){
    __shared__ __align__(16) ushort feat_s[32*392];
    __shared__ float rbf_s[32][NRBF];
    __shared__ float tb_s[32][SBF];
    __shared__ int   src_s[32];
    __shared__ int   dst_s[32];

    const int tid = threadIdx.x;
    const int e0  = blockIdx.x*32;

    if (tid < 32){
        int e = min(e0 + tid, NEDGE-1);
        src_s[tid] = esrc[e];
        dst_s[tid] = edst[e];
        #pragma unroll
        for (int r = 0; r < NRBF; r++) rbf_s[tid][r] = rbf0[(size_t)e*NRBF + r];
        #pragma unroll
        for (int s = 0; s < SBF; s++) tb_s[tid][s] = tb_out[(size_t)e*SBF + s];
    }
    __syncthreads();

    // stage feat: 32 rows x 48 short8 chunks (16 A-src, 16 A-dst, 16 E+tbgate), 6/thread
    #pragma unroll
    for (int j = 0; j < 6; j++){
        int idx = j*256 + tid;
        int m   = idx/48;
        int k8  = idx - m*48;
        short8 h;
        if (k8 < 32){
            const ushort* p = (k8 < 16) ? (Ah + (size_t)src_s[m]*UNITS + k8*8)
                                        : (Ah + (size_t)dst_s[m]*UNITS + (k8-16)*8);
            h = *(const short8*)p;
        } else {
            int q8 = (k8-32)*8;
            int e = min(e0 + m, NEDGE-1);
            short8 eh = *(const short8*)(Eh + (size_t)e*UNITS + q8);
            #pragma unroll
            for (int jj = 0; jj < 8; jj++){
                float ev = bf2f((ushort)eh[jj]);
                float tacc = tbb[q8+jj];
                #pragma unroll
                for (int s = 0; s < SBF; s++)
                    tacc = fmaf(tb_s[m][s], tbg[s*UNITS + q8 + jj], tacc);
                h[jj] = (short)f2bf(ev + tacc);
            }
        }
        *(short8*)&feat_s[m*392 + k8*8] = h;
    }
    __syncthreads();

    const int lane = tid & 63;
    const int w    = tid >> 6;
    const int quad = lane >> 4;
    const int l15  = lane & 15;

    f32x4 zero4 = {0.f, 0.f, 0.f, 0.f};
    f32x4 acc_em[2][2], acc_eg[2][2], acc_am[2][2], acc_ag[2][2];
    #pragma unroll
    for (int mt = 0; mt < 2; mt++)
        #pragma unroll
        for (int ct = 0; ct < 2; ct++){
            acc_em[mt][ct] = zero4; acc_eg[mt][ct] = zero4;
            acc_am[mt][ct] = zero4; acc_ag[mt][ct] = zero4;
        }

    const ushort* a0p = feat_s + l15*392 + quad*8;
    const ushort* a1p = a0p + 16*392;

    // Phase 1: ge over K 0..383; ga over K 0..255 (A-part only)
    for (int ks = 0; ks < 12; ks++){
        short8 a0 = *(const short8*)(a0p + ks*32);
        short8 a1 = *(const short8*)(a1p + ks*32);
        #pragma unroll
        for (int ct = 0; ct < 2; ct++){
            int nt = w*2 + ct;
            size_t boff = ((size_t)(ks*8 + nt)*64 + lane)*8;
            short8 b_em = *(const short8*)(WemP + boff);
            short8 b_eg = *(const short8*)(WegP + boff);
            acc_em[0][ct] = __builtin_amdgcn_mfma_f32_16x16x32_bf16(a0, b_em, acc_em[0][ct], 0, 0, 0);
            acc_em[1][ct] = __builtin_amdgcn_mfma_f32_16x16x32_bf16(a1, b_em, acc_em[1][ct], 0, 0, 0);
            acc_eg[0][ct] = __builtin_amdgcn_mfma_f32_16x16x32_bf16(a0, b_eg, acc_eg[0][ct], 0, 0, 0);
            acc_eg[1][ct] = __builtin_amdgcn_mfma_f32_16x16x32_bf16(a1, b_eg, acc_eg[1][ct], 0, 0, 0);
            if (ks < 8){
                short8 b_am = *(const short8*)(WamP + boff);
                short8 b_ag = *(const short8*)(WagP + boff);
                acc_am[0][ct] = __builtin_amdgcn_mfma_f32_16x16x32_bf16(a0, b_am, acc_am[0][ct], 0, 0, 0);
                acc_am[1][ct] = __builtin_amdgcn_mfma_f32_16x16x32_bf16(a1, b_am, acc_am[1][ct], 0, 0, 0);
                acc_ag[0][ct] = __builtin_amdgcn_mfma_f32_16x16x32_bf16(a0, b_ag, acc_ag[0][ct], 0, 0, 0);
                acc_ag[1][ct] = __builtin_amdgcn_mfma_f32_16x16x32_bf16(a1, b_ag, acc_ag[1][ct], 0, 0, 0);
            }
        }
    }

    // Epilogue 1: edge update (read/write bf16 Eh)
    {
        float bmv[2], bgv[2], elbv[2], elwv[2][NRBF], tbbv[2], tbgv[2][SBF];
        #pragma unroll
        for (int ct = 0; ct < 2; ct++){
            int c = w*32 + ct*16 + l15;
            bmv[ct]  = bem[c];
            bgv[ct]  = beg[c];
            elbv[ct] = eleb_[c];
            #pragma unroll
            for (int r = 0; r < NRBF; r++) elwv[ct][r] = elew_[r*UNITS + c];
            tbbv[ct] = tbb[c];
            #pragma unroll
            for (int s = 0; s < SBF; s++) tbgv[ct][s] = tbg[s*UNITS + c];
        }
        // all phase-1 LDS reads are done; safe to overwrite E-region after barrier
        __syncthreads();
        #pragma unroll
        for (int mt = 0; mt < 2; mt++){
            #pragma unroll
            for (int r = 0; r < 4; r++){
                int ml = mt*16 + quad*4 + r;
                int e  = e0 + ml;
                if (e >= NEDGE) continue;
                #pragma unroll
                for (int ct = 0; ct < 2; ct++){
                    int c = w*32 + ct*16 + l15;
                    float xm = acc_em[mt][ct][r] + bmv[ct];
                    float xg = acc_eg[mt][ct][r] + bgv[ct];
                    float gate = silu(xm)*sigm(xg);
                    float el = elbv[ct];
                    #pragma unroll
                    for (int rr = 0; rr < NRBF; rr++) el = fmaf(rbf_s[ml][rr], elwv[ct][rr], el);
                    float tbc = tbbv[ct];
                    #pragma unroll
                    for (int s = 0; s < SBF; s++) tbc = fmaf(tb_s[ml][s], tbgv[ct][s], tbc);
                    ushort* ep = Eh + (size_t)e*UNITS + c;
                    float enew = bf2f(*ep) + tbc + gate*el;
                    ushort hb = f2bf(enew);
                    *ep = hb;
                    feat_s[ml*392 + 256 + c] = hb;
                }
            }
        }
    }
    __syncthreads();

    // Phase 2: ga over K 256..383 (updated E)
    for (int ks = 8; ks < 12; ks++){
        short8 a0 = *(const short8*)(a0p + ks*32);
        short8 a1 = *(const short8*)(a1p + ks*32);
        #pragma unroll
        for (int ct = 0; ct < 2; ct++){
            int nt = w*2 + ct;
            size_t boff = ((size_t)(ks*8 + nt)*64 + lane)*8;
            short8 b_am = *(const short8*)(WamP + boff);
            short8 b_ag = *(const short8*)(WagP + boff);
            acc_am[0][ct] = __builtin_amdgcn_mfma_f32_16x16x32_bf16(a0, b_am, acc_am[0][ct], 0, 0, 0);
            acc_am[1][ct] = __builtin_amdgcn_mfma_f32_16x16x32_bf16(a1, b_am, acc_am[1][ct], 0, 0, 0);
            acc_ag[0][ct] = __builtin_amdgcn_mfma_f32_16x16x32_bf16(a0, b_ag, acc_ag[0][ct], 0, 0, 0);
            acc_ag[1][ct] = __builtin_amdgcn_mfma_f32_16x16x32_bf16(a1, b_ag, acc_ag[1][ct], 0, 0, 0);
        }
    }

    // Epilogue 2: atom scatter (f32 atomics)
    {
        float bmv[2], bgv[2], elbv[2], elwv[2][NRBF];
        #pragma unroll
        for (int ct = 0; ct < 2; ct++){
            int c = w*32 + ct*16 + l15;
            bmv[ct]  = bam[c];
            bgv[ct]  = bag[c];
            elbv[ct] = elab_[c];
            #pragma unroll
            for (int r = 0; r < NRBF; r++) elwv[ct][r] = elaw_[r*UNITS + c];
        }
        #pragma unroll
        for (int mt = 0; mt < 2; mt++){
            #pragma unroll
            for (int r = 0; r < 4; r++){
                int ml = mt*16 + quad*4 + r;
                int e  = e0 + ml;
                if (e >= NEDGE) continue;
                #pragma unroll
                for (int ct = 0; ct < 2; ct++){
                    int c = w*32 + ct*16 + l15;
                    float xm = acc_am[mt][ct][r] + bmv[ct];
                    float xg = acc_ag[mt][ct][r] + bgv[ct];
                    float gate = silu(xm)*sigm(xg);
                    float el = elbv[ct];
                    #pragma unroll
                    for (int rr = 0; rr < NRBF; rr++) el = fmaf(rbf_s[ml][rr], elwv[ct][rr], el);
                    atomicAdd(&agg[(size_t)src_s[ml]*UNITS + c], gate*el);
                }
            }
        }
    }
}

// ---------------- ghost expansion: f32 chain + bf16 mirror ----------------
__global__ void k_expand(const float* __restrict__ agg, const int* __restrict__ gmap,
                         float* __restrict__ A, ushort* __restrict__ Ah){
    int t = blockIdx.x*blockDim.x + threadIdx.x;
    if (t >= NTOTAL*32) return;
    int i = t >> 5, q = t & 31;
    int row = (i < NLOCAL) ? i : gmap[i - NLOCAL];
    float4 v = ((const float4*)agg)[(size_t)row*32 + q];
    ((float4*)A)[t] = v;
    ushort4 h;
    h.x = f2bf(v.x); h.y = f2bf(v.y); h.z = f2bf(v.z); h.w = f2bf(v.w);
    ((ushort4*)Ah)[t] = h;
}

// ---------------- final readout + global sum ----------------
__global__ void k_final(const float* __restrict__ A, const float* __restrict__ W1,
                        const float* __restrict__ b1, const float* __restrict__ W2,
                        const float* __restrict__ b2, const int* __restrict__ anum,
                        const float* __restrict__ escl, const float* __restrict__ eshf,
                        float* __restrict__ out){
    __shared__ float red[256];
    const int tid  = threadIdx.x;
    const int c    = tid & 127;
    const int half = tid >> 7;
    float b1c = b1[c];
    float w2c = W2[c];
    float b2v = b2[0];
    float tpart = 0.0f;
    const int npairs = NLOCAL/2;
    for (int p = blockIdx.x; p < npairs; p += gridDim.x){
        int a = 2*p + half;
        const float* h = A + (size_t)a*UNITS;
        float acc = b1c;
        for (int k = 0; k < UNITS; k++)
            acc = fmaf(h[k], W1[k*UNITS + c], acc);
        float hid = silu(acc);
        int z = anum[a];
        float sc = escl[z];
        tpart = fmaf(sc*hid, w2c, tpart);
        if (c == 0) tpart += sc*b2v + eshf[z];
    }
    red[tid] = tpart;
    __syncthreads();
    for (int s = 128; s > 0; s >>= 1){
        if (tid < s) red[tid] += red[tid + s];
        __syncthreads();
    }
    if (tid == 0) atomicAdd(out, red[0]);
}

extern "C" void kernel_launch(void* const* d_in, const int* in_sizes, int n_in,
                              void* d_out, int out_size, void* d_ws, size_t ws_size,
                              hipStream_t stream){
    const int*   anum  = (const int*)d_in[0];
    const float* pos   = (const float*)d_in[1];
    const float* cell  = (const float*)d_in[2];
    const float* pbc   = (const float*)d_in[3];
    const int*   esrc  = (const int*)d_in[4];
    const int*   edst  = (const int*)d_in[5];
    const int*   tbi   = (const int*)d_in[6];
    const int*   batch = (const int*)d_in[7];
    const int*   gmap  = (const int*)d_in[8];
    const float* embw  = (const float*)d_in[10];
    const float* encw  = (const float*)d_in[11];
    const float* encb  = (const float*)d_in[12];
    const float* tbaw  = (const float*)d_in[13];
    const float* tbab  = (const float*)d_in[14];
    const float* tbgw  = (const float*)d_in[15];
    const float* tbgb  = (const float*)d_in[16];
    const float* gewm  = (const float*)d_in[17];
    const float* gebm  = (const float*)d_in[18];
    const float* gewg  = (const float*)d_in[19];
    const float* gebg  = (const float*)d_in[20];
    const float* elew  = (const float*)d_in[21];
    const float* eleb  = (const float*)d_in[22];
    const float* gawm  = (const float*)d_in[23];
    const float* gabm  = (const float*)d_in[24];
    const float* gawg  = (const float*)d_in[25];
    const float* gabg  = (const float*)d_in[26];
    const float* elaw  = (const float*)d_in[27];
    const float* elab  = (const float*)d_in[28];
    const float* fw1   = (const float*)d_in[29];
    const float* fb1   = (const float*)d_in[30];
    const float* fw2   = (const float*)d_in[31];
    const float* fb2   = (const float*)d_in[32];
    const float* escl  = (const float*)d_in[33];
    const float* eshf  = (const float*)d_in[34];
    (void)in_sizes; (void)n_in; (void)out_size; (void)ws_size;

    float* ws    = (float*)d_ws;
    float* atomA = ws;                                   // NTOTAL*128 f32
    float* agg   = atomA + (size_t)NTOTAL*UNITS;         // NLOCAL*128 f32
    float* evec  = agg   + (size_t)NLOCAL*UNITS;         // NEDGE*3
    float* elen  = evec  + (size_t)NEDGE*3;              // NEDGE
    float* rbf0  = elen  + (size_t)NEDGE;                // NEDGE*10
    float* tbout = rbf0  + (size_t)NEDGE*NRBF;           // NEDGE*9
    float* amlp  = tbout + (size_t)NEDGE*SBF;            // NLOCAL*9
    ushort* edgeEh = (ushort*)(amlp + (size_t)NLOCAL*SBF);  // NEDGE*128 bf16
    ushort* atomAh = edgeEh + (size_t)NEDGE*UNITS;          // NTOTAL*128 bf16
    ushort* wpack  = atomAh + (size_t)NTOTAL*UNITS;         // 3*4*49152 bf16

    float* out = (float*)d_out;
    hipMemsetAsync(out, 0, sizeof(float), stream);

    k_pack_w<<<(3*4*12*8*64 + 255)/256, 256, 0, stream>>>(gewm, gewg, gawm, gawg, wpack);
    k_edge_geom<<<(NEDGE+255)/256, 256, 0, stream>>>(pos, cell, pbc, esrc, edst, batch,
                                                     evec, elen, rbf0);
    k_embed<<<(NTOTAL*32+255)/256, 256, 0, stream>>>(anum, embw, atomA, atomAh);
    k_edge_enc<<<(NEDGE*32+255)/256, 256, 0, stream>>>(rbf0, encw, encb, edgeEh);

    const int gemm_blocks = (NEDGE+31)/32;
    for (int L = 0; L < NLAYERS; L++){
        const ushort* wpL = wpack + (size_t)L*4*49152;
        k_tb_mlp<<<(NLOCAL+255)/256, 256, 0, stream>>>(atomA,
            tbaw + (size_t)L*UNITS*SBF, tbab + (size_t)L*SBF, amlp);
        hipMemsetAsync(tbout, 0, (size_t)NEDGE*SBF*sizeof(float), stream);
        k_triple<<<(NTRIPLE+255)/256, 256, 0, stream>>>(evec, elen, esrc, tbi, amlp, tbout);
        hipMemcpyAsync(agg, atomA, (size_t)NLOCAL*UNITS*sizeof(float),
                       hipMemcpyDeviceToDevice, stream);
        k_gated_fused<<<gemm_blocks, 256, 0, stream>>>(atomAh, edgeEh, esrc, edst,
            tbout, tbgw + (size_t)L*SBF*UNITS, tbgb + (size_t)L*UNITS,
            wpL + 0*49152, wpL + 1*49152, wpL + 2*49152, wpL + 3*49152,
            gebm + (size_t)L*UNITS, gebg + (size_t)L*UNITS,
            elew + (size_t)L*NRBF*UNITS, eleb + (size_t)L*UNITS,
            gabm + (size_t)L*UNITS, gabg + (size_t)L*UNITS,
            elaw + (size_t)L*NRBF*UNITS, elab + (size_t)L*UNITS,
            rbf0, agg);
        if (L < NLAYERS-1)
            k_expand<<<(NTOTAL*32+255)/256, 256, 0, stream>>>(agg, gmap, atomA, atomAh);
    }
    k_final<<<1024, 256, 0, stream>>>(agg, fw1, fb1, fw2, fb2, anum, escl, eshf, out);
}

// Round 8
// 1446.557 us; speedup vs baseline: 1.7694x; 1.0846x over previous
//
#include <hip/hip_runtime.h>
#include <math.h>

#define UNITS   128
#define NRBF    10
#define SBF     9
#define NLAYERS 3
#define NELEM   95
#define NTOTAL  60000
#define NLOCAL  50000
#define NGHOST  10000
#define NEDGE   250000
#define NTRIPLE 1000000
#define CUTOFF  5.0f
#define TBCUT   4.0f
#define PI_F    3.14159265358979323846f

typedef __attribute__((ext_vector_type(8))) short short8;
typedef __attribute__((ext_vector_type(4))) float f32x4;

// fast sigmoid/silu: v_exp_f32-based (__expf), ~1e-5 rel err — far below bf16 noise
__device__ __forceinline__ float sigm(float x){ return 1.0f/(1.0f+__expf(-x)); }
__device__ __forceinline__ float silu(float x){ return x/(1.0f+__expf(-x)); }
__device__ __forceinline__ float polycut(float r){
    float q = r*(1.0f/TBCUT);
    float q2 = q*q, q3 = q2*q;
    float p = 1.0f - 6.0f*q2*q3 + 15.0f*q2*q2 - 10.0f*q3;
    return (r <= TBCUT) ? p : 0.0f;
}
__device__ __forceinline__ ushort f2bf(float x){
    unsigned u = __float_as_uint(x);
    unsigned r = (u + 0x7fffu + ((u>>16)&1u)) >> 16;
    return (ushort)r;
}
__device__ __forceinline__ float bf2f(ushort h){
    return __uint_as_float(((unsigned)h) << 16);
}
__device__ __forceinline__ void fma4s(float4& acc, float s, const float4& v){
    acc.x = fmaf(s, v.x, acc.x);
    acc.y = fmaf(s, v.y, acc.y);
    acc.z = fmaf(s, v.z, acc.z);
    acc.w = fmaf(s, v.w, acc.w);
}

// ---------------- edge geometry + rbf ----------------
__global__ void k_edge_geom(const float* __restrict__ pos, const float* __restrict__ cell,
                            const float* __restrict__ pbc, const int* __restrict__ src,
                            const int* __restrict__ dst, const int* __restrict__ batch,
                            float* __restrict__ evec, float* __restrict__ elen,
                            float* __restrict__ rbf0){
    int e = blockIdx.x*blockDim.x + threadIdx.x;
    if (e >= NEDGE) return;
    int s = src[e], d = dst[e];
    int b = batch[s];
    const float* C = cell + b*9;
    float p0 = pbc[e*3+0], p1 = pbc[e*3+1], p2 = pbc[e*3+2];
    float vx = pos[s*3+0] - (pos[d*3+0] + p0*C[0] + p1*C[3] + p2*C[6]);
    float vy = pos[s*3+1] - (pos[d*3+1] + p0*C[1] + p1*C[4] + p2*C[7]);
    float vz = pos[s*3+2] - (pos[d*3+2] + p0*C[2] + p1*C[5] + p2*C[8]);
    float r = sqrtf(vx*vx + vy*vy + vz*vz);
    evec[e*3+0] = vx; evec[e*3+1] = vy; evec[e*3+2] = vz;
    elen[e] = r;
    #pragma unroll
    for (int i = 0; i < NRBF; i++){
        float mu = (CUTOFF/(NRBF-1))*i;
        float dm = r - mu;
        rbf0[e*NRBF + i] = __expf(-dm*dm*2.0f);
    }
}

// ---------------- atom embedding gather (f32 + bf16 mirror) ----------------
__global__ void k_embed(const int* __restrict__ anum, const float* __restrict__ embw,
                        float* __restrict__ A, ushort* __restrict__ Ah){
    int t = blockIdx.x*blockDim.x + threadIdx.x;
    if (t >= NTOTAL*32) return;
    int a = t >> 5, q = t & 31;
    float4 v = ((const float4*)embw)[anum[a]*32 + q];
    ((float4*)A)[t] = v;
    ushort4 h;
    h.x = f2bf(v.x); h.y = f2bf(v.y); h.z = f2bf(v.z); h.w = f2bf(v.w);
    ((ushort4*)Ah)[t] = h;
}

// ---------------- edge encoding: Eh = bf16(rbf0 @ Wenc + benc) ----------------
__global__ void k_edge_enc(const float* __restrict__ rbf0, const float* __restrict__ encw,
                           const float* __restrict__ encb, ushort* __restrict__ Eh){
    int t = blockIdx.x*blockDim.x + threadIdx.x;
    if (t >= NEDGE*32) return;
    int e = t >> 5, q = t & 31;
    float4 acc = ((const float4*)encb)[q];
    const float4* W4 = (const float4*)encw;
    #pragma unroll
    for (int r = 0; r < NRBF; r++){
        float rv = rbf0[e*NRBF + r];
        fma4s(acc, rv, W4[r*32 + q]);
    }
    ushort4 h;
    h.x = f2bf(acc.x); h.y = f2bf(acc.y); h.z = f2bf(acc.z); h.w = f2bf(acc.w);
    ((ushort4*)Eh)[t] = h;
}

// ---------------- pack gated-MLP weights into MFMA B-fragment layout ----------------
// layout: [L][mat(ge_m,ge_g,ga_m,ga_g)][kb:12][nt:8][lane:64][j:8] bf16
__global__ void k_pack_w(const float* __restrict__ gewm, const float* __restrict__ gewg,
                         const float* __restrict__ gawm, const float* __restrict__ gawg,
                         ushort* __restrict__ wp){
    int t = blockIdx.x*blockDim.x + threadIdx.x;
    if (t >= 3*4*12*8*64) return;
    int lane = t & 63;
    int nt   = (t>>6) & 7;
    int rest = t >> 9;
    int kb   = rest % 12;
    int r2   = rest / 12;
    int mat  = r2 & 3;
    int L    = r2 >> 2;
    const float* src;
    if      (mat == 0) src = gewm;
    else if (mat == 1) src = gewg;
    else if (mat == 2) src = gawm;
    else               src = gawg;
    src += (size_t)L*384*128;
    int n = nt*16 + (lane & 15);
    int kbase = kb*32 + (lane>>4)*8;
    ushort* dst = wp + (size_t)t*8;
    #pragma unroll
    for (int j = 0; j < 8; j++) dst[j] = f2bf(src[(size_t)(kbase+j)*128 + n]);
}

// ---------------- per-layer: atom sbf mlp ----------------
__global__ void k_tb_mlp(const float* __restrict__ A, const float* __restrict__ W,
                         const float* __restrict__ b, float* __restrict__ out){
    int a = blockIdx.x*blockDim.x + threadIdx.x;
    if (a >= NLOCAL) return;
    float acc[SBF];
    #pragma unroll
    for (int s = 0; s < SBF; s++) acc[s] = b[s];
    const float4* row4 = (const float4*)(A + (size_t)a*UNITS);
    for (int k4 = 0; k4 < 32; k4++){
        float4 v = row4[k4];
        const float* w = W + (k4*4)*SBF;
        #pragma unroll
        for (int s = 0; s < SBF; s++){
            acc[s] = fmaf(v.x, w[s],        acc[s]);
            acc[s] = fmaf(v.y, w[s+SBF],    acc[s]);
            acc[s] = fmaf(v.z, w[s+2*SBF],  acc[s]);
            acc[s] = fmaf(v.w, w[s+3*SBF],  acc[s]);
        }
    }
    #pragma unroll
    for (int s = 0; s < SBF; s++) out[a*SBF + s] = sigm(acc[s]);
}

// ---------------- per-layer: triples -> scatter into tb_out ----------------
__global__ void k_triple(const float* __restrict__ evec, const float* __restrict__ elen,
                         const int* __restrict__ esrc, const int* __restrict__ tbi,
                         const float* __restrict__ amlp, float* __restrict__ tb_out){
    int t = blockIdx.x*blockDim.x + threadIdx.x;
    if (t >= NTRIPLE) return;
    int ij = tbi[2*t], ik = tbi[2*t+1];
    float rij = elen[ij], rik = elen[ik];
    float cutij = polycut(rij), cutik = polycut(rik);
    float cc = cutij*cutik;
    if (cc == 0.0f) return;
    float ax = evec[ij*3+0], ay = evec[ij*3+1], az = evec[ij*3+2];
    float bx = evec[ik*3+0], by = evec[ik*3+1], bz = evec[ik*3+2];
    float dot = ax*bx + ay*by + az*bz;
    float c = dot/(rij*rik + 1e-12f);
    c = fminf(fmaxf(c, -1.0f + 1e-7f), 1.0f - 1e-7f);
    float a0 = 1.0f, a1 = c, a2 = 2.0f*c*c - 1.0f;
    float x = rik*(PI_F/TBCUT);
    float s1, c1;
    sincosf(x, &s1, &c1);
    float s2 = 2.0f*s1*c1;
    float s3 = s1*(3.0f - 4.0f*s1*s1);
    float inv = 1.0f/(rik + 1e-6f);
    float r0 = s1*inv, r1 = s2*inv, r2 = s3*inv;
    int ka = esrc[ik];
    const float* am = amlp + (size_t)ka*SBF;
    float* dst = tb_out + (size_t)ij*SBF;
    atomicAdd(dst+0, r0*a0*am[0]*cc);
    atomicAdd(dst+1, r0*a1*am[1]*cc);
    atomicAdd(dst+2, r0*a2*am[2]*cc);
    atomicAdd(dst+3, r1*a0*am[3]*cc);
    atomicAdd(dst+4, r1*a1*am[4]*cc);
    atomicAdd(dst+5, r1*a2*am[5]*cc);
    atomicAdd(dst+6, r2*a0*am[6]*cc);
    atomicAdd(dst+7, r2*a1*am[7]*cc);
    atomicAdd(dst+8, r2*a2*am[8]*cc);
}

// ---------------- fused per-layer gated blocks (ge + ga) via bf16 MFMA ----------------
// All GEMM-side tensors stored bf16 (Ah, Eh). 32 edges/block, 4 waves.
// feat = [Ah[src] | Ah[dst] | Eh+tbgate] bf16 in LDS (stride 392).
// Phase 1: full-K ge GEMM + A-part (K 0..255) of ga GEMM in one loop.
// Epilogue 1: E_new = staged(E+tbgate) + silu(m)sigm(g)*el_e ; write Eh + LDS bf16.
// Phase 2: remaining K 256..383 of ga GEMM on E_new.
// Epilogue 2: agg[src] += silu(m)sigm(g)*el_a (device atomics, f32).
// NO __launch_bounds__: LDS (28 KB) limits to 5 blocks/CU; let the allocator take
// the VGPRs it needs. (256,5) forced VGPR->48 + scratch spill (R5: 387->700us);
// (256,4) capped VGPR at 64 with heavy rematerialization (R7: VALU-bound 375us).
__global__
void k_gated_fused(const ushort* __restrict__ Ah, ushort* __restrict__ Eh,
                   const int* __restrict__ esrc, const int* __restrict__ edst,
                   const float* __restrict__ tb_out, const float* __restrict__ tbg,
                   const float* __restrict__ tbb,
                   const ushort* __restrict__ WemP, const ushort* __restrict__ WegP,
                   const ushort* __restrict__ WamP, const ushort* __restrict__ WagP,
                   const float* __restrict__ bem, const float* __restrict__ beg,
                   const float* __restrict__ elew_, const float* __restrict__ eleb_,
                   const float* __restrict__ bam, const float* __restrict__ bag,
                   const float* __restrict__ elaw_, const float* __restrict__ elab_,
                   const float* __restrict__ rbf0, float* __restrict__ agg){
    __shared__ __align__(16) ushort feat_s[32*392];
    __shared__ float rbf_s[32][NRBF];
    __shared__ float tb_s[32][SBF];
    __shared__ int   src_s[32];
    __shared__ int   dst_s[32];

    const int tid = threadIdx.x;
    const int e0  = blockIdx.x*32;

    if (tid < 32){
        int e = min(e0 + tid, NEDGE-1);
        src_s[tid] = esrc[e];
        dst_s[tid] = edst[e];
        #pragma unroll
        for (int r = 0; r < NRBF; r++) rbf_s[tid][r] = rbf0[(size_t)e*NRBF + r];
        #pragma unroll
        for (int s = 0; s < SBF; s++) tb_s[tid][s] = tb_out[(size_t)e*SBF + s];
    }
    __syncthreads();

    // stage feat: 32 rows x 48 short8 chunks (16 A-src, 16 A-dst, 16 E+tbgate), 6/thread
    #pragma unroll
    for (int j = 0; j < 6; j++){
        int idx = j*256 + tid;
        int m   = idx/48;
        int k8  = idx - m*48;
        short8 h;
        if (k8 < 32){
            const ushort* p = (k8 < 16) ? (Ah + (size_t)src_s[m]*UNITS + k8*8)
                                        : (Ah + (size_t)dst_s[m]*UNITS + (k8-16)*8);
            h = *(const short8*)p;
        } else {
            int q8 = (k8-32)*8;
            int e = min(e0 + m, NEDGE-1);
            short8 eh = *(const short8*)(Eh + (size_t)e*UNITS + q8);
            // tbgate for 8 consecutive cols: s-outer, float4 row loads (L1-hot)
            float4 t0 = *(const float4*)(tbb + q8);
            float4 t1 = *(const float4*)(tbb + q8 + 4);
            #pragma unroll
            for (int s = 0; s < SBF; s++){
                float ts = tb_s[m][s];
                float4 g0 = *(const float4*)(tbg + s*UNITS + q8);
                float4 g1 = *(const float4*)(tbg + s*UNITS + q8 + 4);
                fma4s(t0, ts, g0);
                fma4s(t1, ts, g1);
            }
            h[0] = (short)f2bf(bf2f((ushort)eh[0]) + t0.x);
            h[1] = (short)f2bf(bf2f((ushort)eh[1]) + t0.y);
            h[2] = (short)f2bf(bf2f((ushort)eh[2]) + t0.z);
            h[3] = (short)f2bf(bf2f((ushort)eh[3]) + t0.w);
            h[4] = (short)f2bf(bf2f((ushort)eh[4]) + t1.x);
            h[5] = (short)f2bf(bf2f((ushort)eh[5]) + t1.y);
            h[6] = (short)f2bf(bf2f((ushort)eh[6]) + t1.z);
            h[7] = (short)f2bf(bf2f((ushort)eh[7]) + t1.w);
        }
        *(short8*)&feat_s[m*392 + k8*8] = h;
    }
    __syncthreads();

    const int lane = tid & 63;
    const int w    = tid >> 6;
    const int quad = lane >> 4;
    const int l15  = lane & 15;

    f32x4 zero4 = {0.f, 0.f, 0.f, 0.f};
    f32x4 acc_em[2][2], acc_eg[2][2], acc_am[2][2], acc_ag[2][2];
    #pragma unroll
    for (int mt = 0; mt < 2; mt++)
        #pragma unroll
        for (int ct = 0; ct < 2; ct++){
            acc_em[mt][ct] = zero4; acc_eg[mt][ct] = zero4;
            acc_am[mt][ct] = zero4; acc_ag[mt][ct] = zero4;
        }

    const ushort* a0p = feat_s + l15*392 + quad*8;
    const ushort* a1p = a0p + 16*392;

    // Phase 1: ge over K 0..383; ga over K 0..255 (A-part only)
    for (int ks = 0; ks < 12; ks++){
        short8 a0 = *(const short8*)(a0p + ks*32);
        short8 a1 = *(const short8*)(a1p + ks*32);
        #pragma unroll
        for (int ct = 0; ct < 2; ct++){
            int nt = w*2 + ct;
            size_t boff = ((size_t)(ks*8 + nt)*64 + lane)*8;
            short8 b_em = *(const short8*)(WemP + boff);
            short8 b_eg = *(const short8*)(WegP + boff);
            acc_em[0][ct] = __builtin_amdgcn_mfma_f32_16x16x32_bf16(a0, b_em, acc_em[0][ct], 0, 0, 0);
            acc_em[1][ct] = __builtin_amdgcn_mfma_f32_16x16x32_bf16(a1, b_em, acc_em[1][ct], 0, 0, 0);
            acc_eg[0][ct] = __builtin_amdgcn_mfma_f32_16x16x32_bf16(a0, b_eg, acc_eg[0][ct], 0, 0, 0);
            acc_eg[1][ct] = __builtin_amdgcn_mfma_f32_16x16x32_bf16(a1, b_eg, acc_eg[1][ct], 0, 0, 0);
            if (ks < 8){
                short8 b_am = *(const short8*)(WamP + boff);
                short8 b_ag = *(const short8*)(WagP + boff);
                acc_am[0][ct] = __builtin_amdgcn_mfma_f32_16x16x32_bf16(a0, b_am, acc_am[0][ct], 0, 0, 0);
                acc_am[1][ct] = __builtin_amdgcn_mfma_f32_16x16x32_bf16(a1, b_am, acc_am[1][ct], 0, 0, 0);
                acc_ag[0][ct] = __builtin_amdgcn_mfma_f32_16x16x32_bf16(a0, b_ag, acc_ag[0][ct], 0, 0, 0);
                acc_ag[1][ct] = __builtin_amdgcn_mfma_f32_16x16x32_bf16(a1, b_ag, acc_ag[1][ct], 0, 0, 0);
            }
        }
    }

    // Epilogue 1: edge update. E+tbgate already staged in feat_s; add gated term.
    {
        float bmv[2], bgv[2], elbv[2], elwv[2][NRBF];
        #pragma unroll
        for (int ct = 0; ct < 2; ct++){
            int c = w*32 + ct*16 + l15;
            bmv[ct]  = bem[c];
            bgv[ct]  = beg[c];
            elbv[ct] = eleb_[c];
            #pragma unroll
            for (int r = 0; r < NRBF; r++) elwv[ct][r] = elew_[r*UNITS + c];
        }
        // all phase-1 LDS reads are done; safe to overwrite E-region after barrier
        __syncthreads();
        #pragma unroll
        for (int mt = 0; mt < 2; mt++){
            #pragma unroll
            for (int r = 0; r < 4; r++){
                int ml = mt*16 + quad*4 + r;
                int e  = e0 + ml;
                if (e >= NEDGE) continue;
                #pragma unroll
                for (int ct = 0; ct < 2; ct++){
                    int c = w*32 + ct*16 + l15;
                    float xm = acc_em[mt][ct][r] + bmv[ct];
                    float xg = acc_eg[mt][ct][r] + bgv[ct];
                    float gate = silu(xm)*sigm(xg);
                    float el = elbv[ct];
                    #pragma unroll
                    for (int rr = 0; rr < NRBF; rr++) el = fmaf(rbf_s[ml][rr], elwv[ct][rr], el);
                    float enew = bf2f(feat_s[ml*392 + 256 + c]) + gate*el;
                    ushort hb = f2bf(enew);
                    Eh[(size_t)e*UNITS + c] = hb;
                    feat_s[ml*392 + 256 + c] = hb;
                }
            }
        }
    }
    __syncthreads();

    // Phase 2: ga over K 256..383 (updated E)
    for (int ks = 8; ks < 12; ks++){
        short8 a0 = *(const short8*)(a0p + ks*32);
        short8 a1 = *(const short8*)(a1p + ks*32);
        #pragma unroll
        for (int ct = 0; ct < 2; ct++){
            int nt = w*2 + ct;
            size_t boff = ((size_t)(ks*8 + nt)*64 + lane)*8;
            short8 b_am = *(const short8*)(WamP + boff);
            short8 b_ag = *(const short8*)(WagP + boff);
            acc_am[0][ct] = __builtin_amdgcn_mfma_f32_16x16x32_bf16(a0, b_am, acc_am[0][ct], 0, 0, 0);
            acc_am[1][ct] = __builtin_amdgcn_mfma_f32_16x16x32_bf16(a1, b_am, acc_am[1][ct], 0, 0, 0);
            acc_ag[0][ct] = __builtin_amdgcn_mfma_f32_16x16x32_bf16(a0, b_ag, acc_ag[0][ct], 0, 0, 0);
            acc_ag[1][ct] = __builtin_amdgcn_mfma_f32_16x16x32_bf16(a1, b_ag, acc_ag[1][ct], 0, 0, 0);
        }
    }

    // Epilogue 2: atom scatter (f32 atomics)
    {
        float bmv[2], bgv[2], elbv[2], elwv[2][NRBF];
        #pragma unroll
        for (int ct = 0; ct < 2; ct++){
            int c = w*32 + ct*16 + l15;
            bmv[ct]  = bam[c];
            bgv[ct]  = bag[c];
            elbv[ct] = elab_[c];
            #pragma unroll
            for (int r = 0; r < NRBF; r++) elwv[ct][r] = elaw_[r*UNITS + c];
        }
        #pragma unroll
        for (int mt = 0; mt < 2; mt++){
            #pragma unroll
            for (int r = 0; r < 4; r++){
                int ml = mt*16 + quad*4 + r;
                int e  = e0 + ml;
                if (e >= NEDGE) continue;
                #pragma unroll
                for (int ct = 0; ct < 2; ct++){
                    int c = w*32 + ct*16 + l15;
                    float xm = acc_am[mt][ct][r] + bmv[ct];
                    float xg = acc_ag[mt][ct][r] + bgv[ct];
                    float gate = silu(xm)*sigm(xg);
                    float el = elbv[ct];
                    #pragma unroll
                    for (int rr = 0; rr < NRBF; rr++) el = fmaf(rbf_s[ml][rr], elwv[ct][rr], el);
                    atomicAdd(&agg[(size_t)src_s[ml]*UNITS + c], gate*el);
                }
            }
        }
    }
}

// ---------------- ghost expansion: f32 chain + bf16 mirror ----------------
__global__ void k_expand(const float* __restrict__ agg, const int* __restrict__ gmap,
                         float* __restrict__ A, ushort* __restrict__ Ah){
    int t = blockIdx.x*blockDim.x + threadIdx.x;
    if (t >= NTOTAL*32) return;
    int i = t >> 5, q = t & 31;
    int row = (i < NLOCAL) ? i : gmap[i - NLOCAL];
    float4 v = ((const float4*)agg)[(size_t)row*32 + q];
    ((float4*)A)[t] = v;
    ushort4 h;
    h.x = f2bf(v.x); h.y = f2bf(v.y); h.z = f2bf(v.z); h.w = f2bf(v.w);
    ((ushort4*)Ah)[t] = h;
}

// ---------------- final readout + global sum ----------------
__global__ void k_final(const float* __restrict__ A, const float* __restrict__ W1,
                        const float* __restrict__ b1, const float* __restrict__ W2,
                        const float* __restrict__ b2, const int* __restrict__ anum,
                        const float* __restrict__ escl, const float* __restrict__ eshf,
                        float* __restrict__ out){
    __shared__ float red[256];
    const int tid  = threadIdx.x;
    const int c    = tid & 127;
    const int half = tid >> 7;
    float b1c = b1[c];
    float w2c = W2[c];
    float b2v = b2[0];
    float tpart = 0.0f;
    const int npairs = NLOCAL/2;
    for (int p = blockIdx.x; p < npairs; p += gridDim.x){
        int a = 2*p + half;
        const float* h = A + (size_t)a*UNITS;
        float acc = b1c;
        for (int k = 0; k < UNITS; k++)
            acc = fmaf(h[k], W1[k*UNITS + c], acc);
        float hid = silu(acc);
        int z = anum[a];
        float sc = escl[z];
        tpart = fmaf(sc*hid, w2c, tpart);
        if (c == 0) tpart += sc*b2v + eshf[z];
    }
    red[tid] = tpart;
    __syncthreads();
    for (int s = 128; s > 0; s >>= 1){
        if (tid < s) red[tid] += red[tid + s];
        __syncthreads();
    }
    if (tid == 0) atomicAdd(out, red[0]);
}

extern "C" void kernel_launch(void* const* d_in, const int* in_sizes, int n_in,
                              void* d_out, int out_size, void* d_ws, size_t ws_size,
                              hipStream_t stream){
    const int*   anum  = (const int*)d_in[0];
    const float* pos   = (const float*)d_in[1];
    const float* cell  = (const float*)d_in[2];
    const float* pbc   = (const float*)d_in[3];
    const int*   esrc  = (const int*)d_in[4];
    const int*   edst  = (const int*)d_in[5];
    const int*   tbi   = (const int*)d_in[6];
    const int*   batch = (const int*)d_in[7];
    const int*   gmap  = (const int*)d_in[8];
    const float* embw  = (const float*)d_in[10];
    const float* encw  = (const float*)d_in[11];
    const float* encb  = (const float*)d_in[12];
    const float* tbaw  = (const float*)d_in[13];
    const float* tbab  = (const float*)d_in[14];
    const float* tbgw  = (const float*)d_in[15];
    const float* tbgb  = (const float*)d_in[16];
    const float* gewm  = (const float*)d_in[17];
    const float* gebm  = (const float*)d_in[18];
    const float* gewg  = (const float*)d_in[19];
    const float* gebg  = (const float*)d_in[20];
    const float* elew  = (const float*)d_in[21];
    const float* eleb  = (const float*)d_in[22];
    const float* gawm  = (const float*)d_in[23];
    const float* gabm  = (const float*)d_in[24];
    const float* gawg  = (const float*)d_in[25];
    const float* gabg  = (const float*)d_in[26];
    const float* elaw  = (const float*)d_in[27];
    const float* elab  = (const float*)d_in[28];
    const float* fw1   = (const float*)d_in[29];
    const float* fb1   = (const float*)d_in[30];
    const float* fw2   = (const float*)d_in[31];
    const float* fb2   = (const float*)d_in[32];
    const float* escl  = (const float*)d_in[33];
    const float* eshf  = (const float*)d_in[34];
    (void)in_sizes; (void)n_in; (void)out_size; (void)ws_size;

    float* ws    = (float*)d_ws;
    float* atomA = ws;                                   // NTOTAL*128 f32
    float* agg   = atomA + (size_t)NTOTAL*UNITS;         // NLOCAL*128 f32
    float* evec  = agg   + (size_t)NLOCAL*UNITS;         // NEDGE*3
    float* elen  = evec  + (size_t)NEDGE*3;              // NEDGE
    float* rbf0  = elen  + (size_t)NEDGE;                // NEDGE*10
    float* tbout = rbf0  + (size_t)NEDGE*NRBF;           // NEDGE*9
    float* amlp  = tbout + (size_t)NEDGE*SBF;            // NLOCAL*9
    ushort* edgeEh = (ushort*)(amlp + (size_t)NLOCAL*SBF);  // NEDGE*128 bf16
    ushort* atomAh = edgeEh + (size_t)NEDGE*UNITS;          // NTOTAL*128 bf16
    ushort* wpack  = atomAh + (size_t)NTOTAL*UNITS;         // 3*4*49152 bf16

    float* out = (float*)d_out;
    hipMemsetAsync(out, 0, sizeof(float), stream);

    k_pack_w<<<(3*4*12*8*64 + 255)/256, 256, 0, stream>>>(gewm, gewg, gawm, gawg, wpack);
    k_edge_geom<<<(NEDGE+255)/256, 256, 0, stream>>>(pos, cell, pbc, esrc, edst, batch,
                                                     evec, elen, rbf0);
    k_embed<<<(NTOTAL*32+255)/256, 256, 0, stream>>>(anum, embw, atomA, atomAh);
    k_edge_enc<<<(NEDGE*32+255)/256, 256, 0, stream>>>(rbf0, encw, encb, edgeEh);

    const int gemm_blocks = (NEDGE+31)/32;
    for (int L = 0; L < NLAYERS; L++){
        const ushort* wpL = wpack + (size_t)L*4*49152;
        k_tb_mlp<<<(NLOCAL+255)/256, 256, 0, stream>>>(atomA,
            tbaw + (size_t)L*UNITS*SBF, tbab + (size_t)L*SBF, amlp);
        hipMemsetAsync(tbout, 0, (size_t)NEDGE*SBF*sizeof(float), stream);
        k_triple<<<(NTRIPLE+255)/256, 256, 0, stream>>>(evec, elen, esrc, tbi, amlp, tbout);
        hipMemcpyAsync(agg, atomA, (size_t)NLOCAL*UNITS*sizeof(float),
                       hipMemcpyDeviceToDevice, stream);
        k_gated_fused<<<gemm_blocks, 256, 0, stream>>>(atomAh, edgeEh, esrc, edst,
            tbout, tbgw + (size_t)L*SBF*UNITS, tbgb + (size_t)L*UNITS,
            wpL + 0*49152, wpL + 1*49152, wpL + 2*49152, wpL + 3*49152,
            gebm + (size_t)L*UNITS, gebg + (size_t)L*UNITS,
            elew + (size_t)L*NRBF*UNITS, eleb + (size_t)L*UNITS,
            gabm + (size_t)L*UNITS, gabg + (size_t)L*UNITS,
            elaw + (size_t)L*NRBF*UNITS, elab + (size_t)L*UNITS,
            rbf0, agg);
        if (L < NLAYERS-1)
            k_expand<<<(NTOTAL*32+255)/256, 256, 0, stream>>>(agg, gmap, atomA, atomAh);
    }
    k_final<<<1024, 256, 0, stream>>>(agg, fw1, fb1, fw2, fb2, anum, escl, eshf, out);
}

// Round 9
// 1431.887 us; speedup vs baseline: 1.7875x; 1.0102x over previous
//
#include <hip/hip_runtime.h>
#include <math.h>

#define UNITS   128
#define NRBF    10
#define SBF     9
#define NLAYERS 3
#define NELEM   95
#define NTOTAL  60000
#define NLOCAL  50000
#define NGHOST  10000
#define NEDGE   250000
#define NTRIPLE 1000000
#define CUTOFF  5.0f
#define TBCUT   4.0f
#define PI_F    3.14159265358979323846f
#define FSTR    424   // feat row stride in ushorts: 13 kb * 32 + 8 pad (848B = 212 dw, gcd(20,32)=4 -> 2-way LDS aliasing, free)

typedef __attribute__((ext_vector_type(8))) short short8;
typedef __attribute__((ext_vector_type(4))) float f32x4;

__device__ __forceinline__ float sigm(float x){ return 1.0f/(1.0f+__expf(-x)); }
__device__ __forceinline__ float silu(float x){ return x/(1.0f+__expf(-x)); }
__device__ __forceinline__ float polycut(float r){
    float q = r*(1.0f/TBCUT);
    float q2 = q*q, q3 = q2*q;
    float p = 1.0f - 6.0f*q2*q3 + 15.0f*q2*q2 - 10.0f*q3;
    return (r <= TBCUT) ? p : 0.0f;
}
__device__ __forceinline__ ushort f2bf(float x){
    unsigned u = __float_as_uint(x);
    unsigned r = (u + 0x7fffu + ((u>>16)&1u)) >> 16;
    return (ushort)r;
}
__device__ __forceinline__ float bf2f(ushort h){
    return __uint_as_float(((unsigned)h) << 16);
}
__device__ __forceinline__ void fma4s(float4& acc, float s, const float4& v){
    acc.x = fmaf(s, v.x, acc.x);
    acc.y = fmaf(s, v.y, acc.y);
    acc.z = fmaf(s, v.z, acc.z);
    acc.w = fmaf(s, v.w, acc.w);
}
__device__ __forceinline__ f32x4 splat4(float x){ f32x4 v = {x,x,x,x}; return v; }
// fast gate: silu(xm)*sigm(xg) = xm / ((1+e^-xm)(1+e^-xg)); v_rcp_f32, ~1e-7 rel err
__device__ __forceinline__ float gatef(float xm, float xg){
    float d = (1.0f+__expf(-xm))*(1.0f+__expf(-xg));
    return xm*__builtin_amdgcn_rcpf(d);
}

// ---------------- edge geometry + rbf ----------------
__global__ void k_edge_geom(const float* __restrict__ pos, const float* __restrict__ cell,
                            const float* __restrict__ pbc, const int* __restrict__ src,
                            const int* __restrict__ dst, const int* __restrict__ batch,
                            float* __restrict__ evec, float* __restrict__ elen,
                            float* __restrict__ rbf0){
    int e = blockIdx.x*blockDim.x + threadIdx.x;
    if (e >= NEDGE) return;
    int s = src[e], d = dst[e];
    int b = batch[s];
    const float* C = cell + b*9;
    float p0 = pbc[e*3+0], p1 = pbc[e*3+1], p2 = pbc[e*3+2];
    float vx = pos[s*3+0] - (pos[d*3+0] + p0*C[0] + p1*C[3] + p2*C[6]);
    float vy = pos[s*3+1] - (pos[d*3+1] + p0*C[1] + p1*C[4] + p2*C[7]);
    float vz = pos[s*3+2] - (pos[d*3+2] + p0*C[2] + p1*C[5] + p2*C[8]);
    float r = sqrtf(vx*vx + vy*vy + vz*vz);
    evec[e*3+0] = vx; evec[e*3+1] = vy; evec[e*3+2] = vz;
    elen[e] = r;
    #pragma unroll
    for (int i = 0; i < NRBF; i++){
        float mu = (CUTOFF/(NRBF-1))*i;
        float dm = r - mu;
        rbf0[e*NRBF + i] = __expf(-dm*dm*2.0f);
    }
}

// ---------------- atom embedding gather (f32 + bf16 mirror) ----------------
__global__ void k_embed(const int* __restrict__ anum, const float* __restrict__ embw,
                        float* __restrict__ A, ushort* __restrict__ Ah){
    int t = blockIdx.x*blockDim.x + threadIdx.x;
    if (t >= NTOTAL*32) return;
    int a = t >> 5, q = t & 31;
    float4 v = ((const float4*)embw)[anum[a]*32 + q];
    ((float4*)A)[t] = v;
    ushort4 h;
    h.x = f2bf(v.x); h.y = f2bf(v.y); h.z = f2bf(v.z); h.w = f2bf(v.w);
    ((ushort4*)Ah)[t] = h;
}

// ---------------- edge encoding: Eh = bf16(rbf0 @ Wenc + benc) ----------------
__global__ void k_edge_enc(const float* __restrict__ rbf0, const float* __restrict__ encw,
                           const float* __restrict__ encb, ushort* __restrict__ Eh){
    int t = blockIdx.x*blockDim.x + threadIdx.x;
    if (t >= NEDGE*32) return;
    int e = t >> 5, q = t & 31;
    float4 acc = ((const float4*)encb)[q];
    const float4* W4 = (const float4*)encw;
    #pragma unroll
    for (int r = 0; r < NRBF; r++){
        float rv = rbf0[e*NRBF + r];
        fma4s(acc, rv, W4[r*32 + q]);
    }
    ushort4 h;
    h.x = f2bf(acc.x); h.y = f2bf(acc.y); h.z = f2bf(acc.z); h.w = f2bf(acc.w);
    ((ushort4*)Eh)[t] = h;
}

// ---------------- pack main gated-MLP weights: [L][mat:4][kb:12][nt:8][lane:64][j:8] ----------------
__global__ void k_pack_w(const float* __restrict__ gewm, const float* __restrict__ gewg,
                         const float* __restrict__ gawm, const float* __restrict__ gawg,
                         ushort* __restrict__ wp){
    int t = blockIdx.x*blockDim.x + threadIdx.x;
    if (t >= 3*4*12*8*64) return;
    int lane = t & 63;
    int nt   = (t>>6) & 7;
    int rest = t >> 9;
    int kb   = rest % 12;
    int r2   = rest / 12;
    int mat  = r2 & 3;
    int L    = r2 >> 2;
    const float* src;
    if      (mat == 0) src = gewm;
    else if (mat == 1) src = gewg;
    else if (mat == 2) src = gawm;
    else               src = gawg;
    src += (size_t)L*384*128;
    int n = nt*16 + (lane & 15);
    int kbase = kb*32 + (lane>>4)*8;
    ushort* dst = wp + (size_t)t*8;
    #pragma unroll
    for (int j = 0; j < 8; j++) dst[j] = f2bf(src[(size_t)(kbase+j)*128 + n]);
}

// ---------------- pack kb12 ext weights: (tbgw @ W_E) rows at aux k=10..18 ----------------
// wext layout: [L][mat:2(em,eg)][nt:8][lane:64][j:8]
__global__ void k_pack_ext(const float* __restrict__ gewm, const float* __restrict__ gewg,
                           const float* __restrict__ tbg, ushort* __restrict__ wext){
    int t = blockIdx.x*blockDim.x + threadIdx.x;
    if (t >= 3*2*512) return;
    int lane = t & 63;
    int nt   = (t>>6) & 7;
    int mat  = (t>>9) & 1;
    int L    = t >> 10;
    const float* W = ((mat==0)? gewm : gewg) + (size_t)L*384*128;
    const float* tg = tbg + (size_t)L*SBF*UNITS;
    int n = nt*16 + (lane & 15);
    ushort* dst = wext + (size_t)t*8;
    #pragma unroll
    for (int j = 0; j < 8; j++){
        int k = (lane>>4)*8 + j;
        float v = 0.0f;
        if (k >= 10 && k <= 18){
            int s = k - 10;
            for (int kk = 0; kk < 128; kk++)
                v = fmaf(tg[s*UNITS+kk], W[(size_t)(256+kk)*128 + n], v);
        }
        dst[j] = f2bf(v);
    }
}

// ---------------- pack aux B mats: el_e (elew @ k0..9), el_a (elaw), tbgate (tbg @ k10..18) ----------------
// waux layout: [L][mat:3][nt:8][lane:64][j:8]
__global__ void k_pack_aux(const float* __restrict__ elew, const float* __restrict__ elaw,
                           const float* __restrict__ tbg, ushort* __restrict__ waux){
    int t = blockIdx.x*blockDim.x + threadIdx.x;
    if (t >= 3*3*512) return;
    int lane = t & 63;
    int nt   = (t>>6) & 7;
    int rest = t >> 9;
    int mat  = rest % 3;
    int L    = rest / 3;
    int n = nt*16 + (lane & 15);
    ushort* dst = waux + (size_t)t*8;
    #pragma unroll
    for (int j = 0; j < 8; j++){
        int k = (lane>>4)*8 + j;
        float v = 0.0f;
        if (mat == 0){ if (k < 10) v = elew[(size_t)L*NRBF*UNITS + k*UNITS + n]; }
        else if (mat == 1){ if (k < 10) v = elaw[(size_t)L*NRBF*UNITS + k*UNITS + n]; }
        else { if (k >= 10 && k <= 18) v = tbg[(size_t)L*SBF*UNITS + (k-10)*UNITS + n]; }
        dst[j] = f2bf(v);
    }
}

// ---------------- bias totals: btot[L][mat:2][128] = be + tbb @ W_E ----------------
__global__ void k_pack_bias(const float* __restrict__ gewm, const float* __restrict__ gewg,
                            const float* __restrict__ gebm, const float* __restrict__ gebg,
                            const float* __restrict__ tbb, float* __restrict__ btot){
    int t = blockIdx.x*blockDim.x + threadIdx.x;
    if (t >= 3*2*128) return;
    int n = t & 127;
    int mat = (t>>7) & 1;
    int L = t >> 8;
    const float* W = ((mat==0)? gewm : gewg) + (size_t)L*384*128;
    const float* be = ((mat==0)? gebm : gebg) + (size_t)L*UNITS;
    const float* tb = tbb + (size_t)L*UNITS;
    float v = be[n];
    for (int kk = 0; kk < 128; kk++)
        v = fmaf(tb[kk], W[(size_t)(256+kk)*128 + n], v);
    btot[t] = v;
}

// ---------------- per-layer: atom sbf mlp (+ fused agg <- atomA copy) ----------------
__global__ void k_tb_mlp(const float* __restrict__ A, const float* __restrict__ W,
                         const float* __restrict__ b, float* __restrict__ out,
                         float* __restrict__ agg){
    int a = blockIdx.x*blockDim.x + threadIdx.x;
    if (a >= NLOCAL) return;
    float acc[SBF];
    #pragma unroll
    for (int s = 0; s < SBF; s++) acc[s] = b[s];
    const float4* row4 = (const float4*)(A + (size_t)a*UNITS);
    float4* agg4 = (float4*)(agg + (size_t)a*UNITS);
    for (int k4 = 0; k4 < 32; k4++){
        float4 v = row4[k4];
        agg4[k4] = v;
        const float* w = W + (k4*4)*SBF;
        #pragma unroll
        for (int s = 0; s < SBF; s++){
            acc[s] = fmaf(v.x, w[s],        acc[s]);
            acc[s] = fmaf(v.y, w[s+SBF],    acc[s]);
            acc[s] = fmaf(v.z, w[s+2*SBF],  acc[s]);
            acc[s] = fmaf(v.w, w[s+3*SBF],  acc[s]);
        }
    }
    #pragma unroll
    for (int s = 0; s < SBF; s++) out[a*SBF + s] = sigm(acc[s]);
}

// ---------------- one-time triple compaction (layer-independent geometry) ----------------
__global__ void k_triple_compact(const float* __restrict__ evec, const float* __restrict__ elen,
                                 const int* __restrict__ esrc, const int* __restrict__ tbi,
                                 int* __restrict__ cnt, int* __restrict__ c_ij,
                                 int* __restrict__ c_ka, float* __restrict__ c_cf){
    int t = blockIdx.x*blockDim.x + threadIdx.x;
    if (t >= NTRIPLE) return;
    int ij = tbi[2*t], ik = tbi[2*t+1];
    float rij = elen[ij], rik = elen[ik];
    float cc = polycut(rij)*polycut(rik);
    if (cc == 0.0f) return;   // exact zero contribution
    float ax = evec[ij*3+0], ay = evec[ij*3+1], az = evec[ij*3+2];
    float bx = evec[ik*3+0], by = evec[ik*3+1], bz = evec[ik*3+2];
    float dot = ax*bx + ay*by + az*bz;
    float c = dot/(rij*rik + 1e-12f);
    c = fminf(fmaxf(c, -1.0f + 1e-7f), 1.0f - 1e-7f);
    float a0 = 1.0f, a1 = c, a2 = 2.0f*c*c - 1.0f;
    float x = rik*(PI_F/TBCUT);
    float s1, c1;
    sincosf(x, &s1, &c1);
    float s2 = 2.0f*s1*c1;
    float s3 = s1*(3.0f - 4.0f*s1*s1);
    float inv = 1.0f/(rik + 1e-6f);
    float r0 = s1*inv, r1 = s2*inv, r2 = s3*inv;
    int idx = atomicAdd(cnt, 1);
    c_ij[idx] = ij;
    c_ka[idx] = esrc[ik];
    c_cf[idx + 0*NTRIPLE] = r0*a0*cc;
    c_cf[idx + 1*NTRIPLE] = r0*a1*cc;
    c_cf[idx + 2*NTRIPLE] = r0*a2*cc;
    c_cf[idx + 3*NTRIPLE] = r1*a0*cc;
    c_cf[idx + 4*NTRIPLE] = r1*a1*cc;
    c_cf[idx + 5*NTRIPLE] = r1*a2*cc;
    c_cf[idx + 6*NTRIPLE] = r2*a0*cc;
    c_cf[idx + 7*NTRIPLE] = r2*a1*cc;
    c_cf[idx + 8*NTRIPLE] = r2*a2*cc;
}

// ---------------- per-layer: apply compacted triples ----------------
__global__ void k_triple_apply(const int* __restrict__ cnt, const int* __restrict__ c_ij,
                               const int* __restrict__ c_ka, const float* __restrict__ c_cf,
                               const float* __restrict__ amlp, float* __restrict__ tb_out){
    int t = blockIdx.x*blockDim.x + threadIdx.x;
    if (t >= *cnt) return;
    int ij = c_ij[t], ka = c_ka[t];
    const float* am = amlp + (size_t)ka*SBF;
    float* dst = tb_out + (size_t)ij*SBF;
    #pragma unroll
    for (int s = 0; s < SBF; s++)
        atomicAdd(dst+s, c_cf[t + s*NTRIPLE]*am[s]);
}

// ---------------- fused per-layer gated blocks (ge + ga), all-MFMA ----------------
// feat (bf16 LDS, stride FSTR): kb0-7 = Ah[src]|Ah[dst], kb8-11 = Eh (pure copy),
// kb12 aux = [rbf(10) | tb9(9) | zeros]. Biases via accumulator splat-init.
// ge GEMM runs kb0..12 (ext weights carry tbgw@W_E); el_e/el_a/tbgate computed by
// MFMA vs aux fragment -> results land in C-layout exactly where epilogues need them.
// Phase1: ge full-K + ga kb0..7 + aux(te,le). Epi1: E_new -> Eh + feat. Phase2: ga kb8..11 + aux(la).
// Epi2: agg[src] += gate*el_a. NO launch_bounds (R5: forcing 5 waves spilled; R7: 64-cap remat-bound).
__global__
void k_gated_fused(const ushort* __restrict__ Ah, ushort* __restrict__ Eh,
                   const int* __restrict__ esrc, const int* __restrict__ edst,
                   const float* __restrict__ rbf0, const float* __restrict__ tb_out,
                   const ushort* __restrict__ Wem, const ushort* __restrict__ Weg,
                   const ushort* __restrict__ Wam, const ushort* __restrict__ Wag,
                   const ushort* __restrict__ WxM, const ushort* __restrict__ WxG,
                   const ushort* __restrict__ Ble, const ushort* __restrict__ Bla,
                   const ushort* __restrict__ Bte,
                   const float* __restrict__ btm, const float* __restrict__ btg,
                   const float* __restrict__ bam, const float* __restrict__ bag,
                   const float* __restrict__ tbb, const float* __restrict__ eleb,
                   const float* __restrict__ elab,
                   float* __restrict__ agg){
    __shared__ __align__(16) ushort feat_s[32*FSTR];
    __shared__ int src_s[32];
    __shared__ int dst_s[32];

    const int tid = threadIdx.x;
    const int e0  = blockIdx.x*32;

    if (tid < 32){
        int e = min(e0 + tid, NEDGE-1);
        src_s[tid] = esrc[e];
        dst_s[tid] = edst[e];
    }
    __syncthreads();

    // main staging: 32 rows x 48 short8, pure bf16 copies, 6/thread
    #pragma unroll
    for (int j = 0; j < 6; j++){
        int idx = j*256 + tid;
        int m   = idx/48;
        int k8  = idx - m*48;
        const ushort* p;
        if (k8 < 16)      p = Ah + (size_t)src_s[m]*UNITS + k8*8;
        else if (k8 < 32) p = Ah + (size_t)dst_s[m]*UNITS + (k8-16)*8;
        else {
            int e = min(e0 + m, NEDGE-1);
            p = Eh + (size_t)e*UNITS + (k8-32)*8;
        }
        *(short8*)&feat_s[m*FSTR + k8*8] = *(const short8*)p;
    }
    // aux staging: 32 rows x 4 short8 = [rbf | tb9 | 0]
    if (tid < 128){
        int m = tid >> 2, j8 = tid & 3;
        int e = min(e0 + m, NEDGE-1);
        short8 h;
        #pragma unroll
        for (int jj = 0; jj < 8; jj++){
            int k = j8*8 + jj;
            float x = 0.0f;
            if (k < 10)      x = rbf0[(size_t)e*NRBF + k];
            else if (k < 19) x = tb_out[(size_t)e*SBF + (k-10)];
            h[jj] = (short)f2bf(x);
        }
        *(short8*)&feat_s[m*FSTR + 384 + j8*8] = h;
    }
    __syncthreads();

    const int lane = tid & 63;
    const int w    = tid >> 6;
    const int quad = lane >> 4;
    const int l15  = lane & 15;

    // per-column biases -> acc splat init (C layout: all 4 regs share the column)
    float btm_c[2], btg_c[2], bam_c[2], bag_c[2], tbb_c[2], leb_c[2];
    #pragma unroll
    for (int ct = 0; ct < 2; ct++){
        int c = w*32 + ct*16 + l15;
        btm_c[ct] = btm[c]; btg_c[ct] = btg[c];
        bam_c[ct] = bam[c]; bag_c[ct] = bag[c];
        tbb_c[ct] = tbb[c]; leb_c[ct] = eleb[c];
    }

    f32x4 acc_em[2][2], acc_eg[2][2], acc_am[2][2], acc_ag[2][2], acc_te[2][2], acc_le[2][2];
    #pragma unroll
    for (int mt = 0; mt < 2; mt++)
        #pragma unroll
        for (int ct = 0; ct < 2; ct++){
            acc_em[mt][ct] = splat4(btm_c[ct]); acc_eg[mt][ct] = splat4(btg_c[ct]);
            acc_am[mt][ct] = splat4(bam_c[ct]); acc_ag[mt][ct] = splat4(bag_c[ct]);
            acc_te[mt][ct] = splat4(tbb_c[ct]); acc_le[mt][ct] = splat4(leb_c[ct]);
        }

    const ushort* a0p = feat_s + l15*FSTR + quad*8;
    const ushort* a1p = a0p + 16*FSTR;

    // Phase 1: ge kb0..11; ga kb0..7
    for (int ks = 0; ks < 12; ks++){
        short8 a0 = *(const short8*)(a0p + ks*32);
        short8 a1 = *(const short8*)(a1p + ks*32);
        #pragma unroll
        for (int ct = 0; ct < 2; ct++){
            int nt = w*2 + ct;
            size_t boff = ((size_t)(ks*8 + nt)*64 + lane)*8;
            short8 b_em = *(const short8*)(Wem + boff);
            short8 b_eg = *(const short8*)(Weg + boff);
            acc_em[0][ct] = __builtin_amdgcn_mfma_f32_16x16x32_bf16(a0, b_em, acc_em[0][ct], 0, 0, 0);
            acc_em[1][ct] = __builtin_amdgcn_mfma_f32_16x16x32_bf16(a1, b_em, acc_em[1][ct], 0, 0, 0);
            acc_eg[0][ct] = __builtin_amdgcn_mfma_f32_16x16x32_bf16(a0, b_eg, acc_eg[0][ct], 0, 0, 0);
            acc_eg[1][ct] = __builtin_amdgcn_mfma_f32_16x16x32_bf16(a1, b_eg, acc_eg[1][ct], 0, 0, 0);
            if (ks < 8){
                short8 b_am = *(const short8*)(Wam + boff);
                short8 b_ag = *(const short8*)(Wag + boff);
                acc_am[0][ct] = __builtin_amdgcn_mfma_f32_16x16x32_bf16(a0, b_am, acc_am[0][ct], 0, 0, 0);
                acc_am[1][ct] = __builtin_amdgcn_mfma_f32_16x16x32_bf16(a1, b_am, acc_am[1][ct], 0, 0, 0);
                acc_ag[0][ct] = __builtin_amdgcn_mfma_f32_16x16x32_bf16(a0, b_ag, acc_ag[0][ct], 0, 0, 0);
                acc_ag[1][ct] = __builtin_amdgcn_mfma_f32_16x16x32_bf16(a1, b_ag, acc_ag[1][ct], 0, 0, 0);
            }
        }
    }
    // kb12 (aux fragment): ge ext + te + le
    short8 a0x = *(const short8*)(a0p + 384);
    short8 a1x = *(const short8*)(a1p + 384);
    #pragma unroll
    for (int ct = 0; ct < 2; ct++){
        size_t bx = ((size_t)(w*2 + ct)*64 + lane)*8;
        short8 b_xm = *(const short8*)(WxM + bx);
        short8 b_xg = *(const short8*)(WxG + bx);
        short8 b_te = *(const short8*)(Bte + bx);
        short8 b_le = *(const short8*)(Ble + bx);
        acc_em[0][ct] = __builtin_amdgcn_mfma_f32_16x16x32_bf16(a0x, b_xm, acc_em[0][ct], 0, 0, 0);
        acc_em[1][ct] = __builtin_amdgcn_mfma_f32_16x16x32_bf16(a1x, b_xm, acc_em[1][ct], 0, 0, 0);
        acc_eg[0][ct] = __builtin_amdgcn_mfma_f32_16x16x32_bf16(a0x, b_xg, acc_eg[0][ct], 0, 0, 0);
        acc_eg[1][ct] = __builtin_amdgcn_mfma_f32_16x16x32_bf16(a1x, b_xg, acc_eg[1][ct], 0, 0, 0);
        acc_te[0][ct] = __builtin_amdgcn_mfma_f32_16x16x32_bf16(a0x, b_te, acc_te[0][ct], 0, 0, 0);
        acc_te[1][ct] = __builtin_amdgcn_mfma_f32_16x16x32_bf16(a1x, b_te, acc_te[1][ct], 0, 0, 0);
        acc_le[0][ct] = __builtin_amdgcn_mfma_f32_16x16x32_bf16(a0x, b_le, acc_le[0][ct], 0, 0, 0);
        acc_le[1][ct] = __builtin_amdgcn_mfma_f32_16x16x32_bf16(a1x, b_le, acc_le[1][ct], 0, 0, 0);
    }

    // Epilogue 1: E_new = E_old + tbgate + gate*el_e  (all pieces in C layout)
    __syncthreads();   // all waves done reading feat in phase 1
    #pragma unroll
    for (int mt = 0; mt < 2; mt++){
        #pragma unroll
        for (int r = 0; r < 4; r++){
            int ml = mt*16 + quad*4 + r;
            int e  = e0 + ml;
            if (e >= NEDGE) continue;
            #pragma unroll
            for (int ct = 0; ct < 2; ct++){
                int c = w*32 + ct*16 + l15;
                float gate = gatef(acc_em[mt][ct][r], acc_eg[mt][ct][r]);
                float enew = bf2f(feat_s[ml*FSTR + 256 + c])
                           + acc_te[mt][ct][r] + gate*acc_le[mt][ct][r];
                ushort hb = f2bf(enew);
                feat_s[ml*FSTR + 256 + c] = hb;
                Eh[(size_t)e*UNITS + c] = hb;
            }
        }
    }
    __syncthreads();

    // Phase 2: ga kb8..11 on E_new + la
    for (int ks = 8; ks < 12; ks++){
        short8 a0 = *(const short8*)(a0p + ks*32);
        short8 a1 = *(const short8*)(a1p + ks*32);
        #pragma unroll
        for (int ct = 0; ct < 2; ct++){
            int nt = w*2 + ct;
            size_t boff = ((size_t)(ks*8 + nt)*64 + lane)*8;
            short8 b_am = *(const short8*)(Wam + boff);
            short8 b_ag = *(const short8*)(Wag + boff);
            acc_am[0][ct] = __builtin_amdgcn_mfma_f32_16x16x32_bf16(a0, b_am, acc_am[0][ct], 0, 0, 0);
            acc_am[1][ct] = __builtin_amdgcn_mfma_f32_16x16x32_bf16(a1, b_am, acc_am[1][ct], 0, 0, 0);
            acc_ag[0][ct] = __builtin_amdgcn_mfma_f32_16x16x32_bf16(a0, b_ag, acc_ag[0][ct], 0, 0, 0);
            acc_ag[1][ct] = __builtin_amdgcn_mfma_f32_16x16x32_bf16(a1, b_ag, acc_ag[1][ct], 0, 0, 0);
        }
    }
    f32x4 acc_la[2][2];
    {
        float lab_c[2];
        #pragma unroll
        for (int ct = 0; ct < 2; ct++) lab_c[ct] = elab[w*32 + ct*16 + l15];
        #pragma unroll
        for (int ct = 0; ct < 2; ct++){
            acc_la[0][ct] = splat4(lab_c[ct]);
            acc_la[1][ct] = splat4(lab_c[ct]);
            size_t bx = ((size_t)(w*2 + ct)*64 + lane)*8;
            short8 b_la = *(const short8*)(Bla + bx);
            acc_la[0][ct] = __builtin_amdgcn_mfma_f32_16x16x32_bf16(a0x, b_la, acc_la[0][ct], 0, 0, 0);
            acc_la[1][ct] = __builtin_amdgcn_mfma_f32_16x16x32_bf16(a1x, b_la, acc_la[1][ct], 0, 0, 0);
        }
    }

    // Epilogue 2: atom scatter
    #pragma unroll
    for (int mt = 0; mt < 2; mt++){
        #pragma unroll
        for (int r = 0; r < 4; r++){
            int ml = mt*16 + quad*4 + r;
            int e  = e0 + ml;
            if (e >= NEDGE) continue;
            #pragma unroll
            for (int ct = 0; ct < 2; ct++){
                int c = w*32 + ct*16 + l15;
                float gate = gatef(acc_am[mt][ct][r], acc_ag[mt][ct][r]);
                atomicAdd(&agg[(size_t)src_s[ml]*UNITS + c], gate*acc_la[mt][ct][r]);
            }
        }
    }
}

// ---------------- ghost expansion: f32 chain + bf16 mirror ----------------
__global__ void k_expand(const float* __restrict__ agg, const int* __restrict__ gmap,
                         float* __restrict__ A, ushort* __restrict__ Ah){
    int t = blockIdx.x*blockDim.x + threadIdx.x;
    if (t >= NTOTAL*32) return;
    int i = t >> 5, q = t & 31;
    int row = (i < NLOCAL) ? i : gmap[i - NLOCAL];
    float4 v = ((const float4*)agg)[(size_t)row*32 + q];
    ((float4*)A)[t] = v;
    ushort4 h;
    h.x = f2bf(v.x); h.y = f2bf(v.y); h.z = f2bf(v.z); h.w = f2bf(v.w);
    ((ushort4*)Ah)[t] = h;
}

// ---------------- final readout + global sum ----------------
__global__ void k_final(const float* __restrict__ A, const float* __restrict__ W1,
                        const float* __restrict__ b1, const float* __restrict__ W2,
                        const float* __restrict__ b2, const int* __restrict__ anum,
                        const float* __restrict__ escl, const float* __restrict__ eshf,
                        float* __restrict__ out){
    __shared__ float red[256];
    const int tid  = threadIdx.x;
    const int c    = tid & 127;
    const int half = tid >> 7;
    float b1c = b1[c];
    float w2c = W2[c];
    float b2v = b2[0];
    float tpart = 0.0f;
    const int npairs = NLOCAL/2;
    for (int p = blockIdx.x; p < npairs; p += gridDim.x){
        int a = 2*p + half;
        const float* h = A + (size_t)a*UNITS;
        float acc = b1c;
        for (int k = 0; k < UNITS; k++)
            acc = fmaf(h[k], W1[k*UNITS + c], acc);
        float hid = silu(acc);
        int z = anum[a];
        float sc = escl[z];
        tpart = fmaf(sc*hid, w2c, tpart);
        if (c == 0) tpart += sc*b2v + eshf[z];
    }
    red[tid] = tpart;
    __syncthreads();
    for (int s = 128; s > 0; s >>= 1){
        if (tid < s) red[tid] += red[tid + s];
        __syncthreads();
    }
    if (tid == 0) atomicAdd(out, red[0]);
}

extern "C" void kernel_launch(void* const* d_in, const int* in_sizes, int n_in,
                              void* d_out, int out_size, void* d_ws, size_t ws_size,
                              hipStream_t stream){
    const int*   anum  = (const int*)d_in[0];
    const float* pos   = (const float*)d_in[1];
    const float* cell  = (const float*)d_in[2];
    const float* pbc   = (const float*)d_in[3];
    const int*   esrc  = (const int*)d_in[4];
    const int*   edst  = (const int*)d_in[5];
    const int*   tbi   = (const int*)d_in[6];
    const int*   batch = (const int*)d_in[7];
    const int*   gmap  = (const int*)d_in[8];
    const float* embw  = (const float*)d_in[10];
    const float* encw  = (const float*)d_in[11];
    const float* encb  = (const float*)d_in[12];
    const float* tbaw  = (const float*)d_in[13];
    const float* tbab  = (const float*)d_in[14];
    const float* tbgw  = (const float*)d_in[15];
    const float* tbgb  = (const float*)d_in[16];
    const float* gewm  = (const float*)d_in[17];
    const float* gebm  = (const float*)d_in[18];
    const float* gewg  = (const float*)d_in[19];
    const float* gebg  = (const float*)d_in[20];
    const float* elew  = (const float*)d_in[21];
    const float* eleb  = (const float*)d_in[22];
    const float* gawm  = (const float*)d_in[23];
    const float* gabm  = (const float*)d_in[24];
    const float* gawg  = (const float*)d_in[25];
    const float* gabg  = (const float*)d_in[26];
    const float* elaw  = (const float*)d_in[27];
    const float* elab  = (const float*)d_in[28];
    const float* fw1   = (const float*)d_in[29];
    const float* fb1   = (const float*)d_in[30];
    const float* fw2   = (const float*)d_in[31];
    const float* fb2   = (const float*)d_in[32];
    const float* escl  = (const float*)d_in[33];
    const float* eshf  = (const float*)d_in[34];
    (void)in_sizes; (void)n_in; (void)out_size; (void)ws_size;

    float* ws    = (float*)d_ws;
    float* atomA = ws;                                   // NTOTAL*128 f32
    float* agg   = atomA + (size_t)NTOTAL*UNITS;         // NLOCAL*128 f32
    float* evec  = agg   + (size_t)NLOCAL*UNITS;         // NEDGE*3
    float* elen  = evec  + (size_t)NEDGE*3;              // NEDGE
    float* rbf0  = elen  + (size_t)NEDGE;                // NEDGE*10
    float* tbout = rbf0  + (size_t)NEDGE*NRBF;           // NEDGE*9
    float* amlp  = tbout + (size_t)NEDGE*SBF;            // NLOCAL*9
    float* btot  = amlp  + (size_t)NLOCAL*SBF;           // 3*2*128
    int*   tcnt  = (int*)(btot + 3*2*128);               // 1 (+3 pad)
    int*   c_ij  = tcnt + 4;                             // NTRIPLE
    int*   c_ka  = c_ij + NTRIPLE;                       // NTRIPLE
    float* c_cf  = (float*)(c_ka + NTRIPLE);             // 9*NTRIPLE
    ushort* edgeEh = (ushort*)(c_cf + (size_t)9*NTRIPLE);   // NEDGE*128 bf16
    ushort* atomAh = edgeEh + (size_t)NEDGE*UNITS;          // NTOTAL*128 bf16
    ushort* wmain  = atomAh + (size_t)NTOTAL*UNITS;         // 3*4*49152
    ushort* wext   = wmain + (size_t)3*4*49152;             // 3*2*4096
    ushort* waux   = wext  + (size_t)3*2*4096;              // 3*3*4096

    float* out = (float*)d_out;
    hipMemsetAsync(out, 0, sizeof(float), stream);
    hipMemsetAsync(tcnt, 0, sizeof(int), stream);

    k_pack_w   <<<(3*4*12*8*64 + 255)/256, 256, 0, stream>>>(gewm, gewg, gawm, gawg, wmain);
    k_pack_ext <<<(3*2*512 + 255)/256, 256, 0, stream>>>(gewm, gewg, tbgw, wext);
    k_pack_aux <<<(3*3*512 + 255)/256, 256, 0, stream>>>(elew, elaw, tbgw, waux);
    k_pack_bias<<<(3*2*128 + 255)/256, 256, 0, stream>>>(gewm, gewg, gebm, gebg, tbgb, btot);
    k_edge_geom<<<(NEDGE+255)/256, 256, 0, stream>>>(pos, cell, pbc, esrc, edst, batch,
                                                     evec, elen, rbf0);
    k_embed<<<(NTOTAL*32+255)/256, 256, 0, stream>>>(anum, embw, atomA, atomAh);
    k_edge_enc<<<(NEDGE*32+255)/256, 256, 0, stream>>>(rbf0, encw, encb, edgeEh);
    k_triple_compact<<<(NTRIPLE+255)/256, 256, 0, stream>>>(evec, elen, esrc, tbi,
                                                            tcnt, c_ij, c_ka, c_cf);

    const int gemm_blocks = (NEDGE+31)/32;
    for (int L = 0; L < NLAYERS; L++){
        const ushort* wmL = wmain + (size_t)L*4*49152;
        const ushort* wxL = wext  + (size_t)L*2*4096;
        const ushort* waL = waux  + (size_t)L*3*4096;
        k_tb_mlp<<<(NLOCAL+255)/256, 256, 0, stream>>>(atomA,
            tbaw + (size_t)L*UNITS*SBF, tbab + (size_t)L*SBF, amlp, agg);
        hipMemsetAsync(tbout, 0, (size_t)NEDGE*SBF*sizeof(float), stream);
        k_triple_apply<<<(NTRIPLE+255)/256, 256, 0, stream>>>(tcnt, c_ij, c_ka, c_cf,
                                                              amlp, tbout);
        k_gated_fused<<<gemm_blocks, 256, 0, stream>>>(atomAh, edgeEh, esrc, edst,
            rbf0, tbout,
            wmL + 0*49152, wmL + 1*49152, wmL + 2*49152, wmL + 3*49152,
            wxL + 0*4096,  wxL + 1*4096,
            waL + 0*4096,  waL + 1*4096, waL + 2*4096,
            btot + (size_t)L*2*128, btot + (size_t)L*2*128 + 128,
            gabm + (size_t)L*UNITS, gabg + (size_t)L*UNITS,
            tbgb + (size_t)L*UNITS, eleb + (size_t)L*UNITS, elab + (size_t)L*UNITS,
            agg);
        if (L < NLAYERS-1)
            k_expand<<<(NTOTAL*32+255)/256, 256, 0, stream>>>(agg, gmap, atomA, atomAh);
    }
    k_final<<<1024, 256, 0, stream>>>(agg, fw1, fb1, fw2, fb2, anum, escl, eshf, out);
}